// Round 5
// baseline (2231.727 us; speedup 1.0000x reference)
//
#include <hip/hip_runtime.h>
#include <hip/hip_bf16.h>
#include <math.h>

typedef __attribute__((ext_vector_type(4))) float f32x4;
typedef __attribute__((ext_vector_type(8))) short bf16x8;

constexpr int kB = 128, kT = 20, kH = 1024, kE = 512, kP = 36, kRaw = 2048, kV = 12000;

__device__ __forceinline__ float sigf(float x) { return 1.0f / (1.0f + expf(-x)); }

#define AS1C const __attribute__((address_space(1))) void*
#define AS3P __attribute__((address_space(3))) void*

// ---------------------------------------------------------------- utilities
__global__ __launch_bounds__(256) void zero_f32(float* p, int n) {
  int i = blockIdx.x * 256 + threadIdx.x;
  if (i < n) p[i] = 0.0f;
}
__global__ __launch_bounds__(256) void zero_bf16(__hip_bfloat16* p, int n) {
  int i = blockIdx.x * 256 + threadIdx.x;
  if (i < n) p[i] = __float2bfloat16(0.0f);
}
__global__ __launch_bounds__(256) void f32_to_bf16(const float* __restrict__ src,
                                                   __hip_bfloat16* __restrict__ dst, int n4) {
  int i = blockIdx.x * 256 + threadIdx.x;
  if (i >= n4) return;
  float4 v = reinterpret_cast<const float4*>(src)[i];
  __hip_bfloat16* d = dst + (size_t)i * 4;
  d[0] = __float2bfloat16(v.x); d[1] = __float2bfloat16(v.y);
  d[2] = __float2bfloat16(v.z); d[3] = __float2bfloat16(v.w);
}

// dst_row = perm(n + n_off); dst[dst_row][k + k_off] = bf16(src[k][n]).
// mode 0: identity. mode 1: 5-gate interleave (packed=(h>>4)*80+g*16+(h&15)).
// mode 2: 4-gate interleave (packed=(h>>4)*64+g*16+(h&15)).
__global__ __launch_bounds__(256) void transpose_to_bf16(const float* __restrict__ src, int ld_src,
                                                         int Kblk, int Nblk,
                                                         __hip_bfloat16* __restrict__ dst, int lddst,
                                                         int k_off, int n_off, int mode) {
  __shared__ float t[32][33];
  int n0 = blockIdx.x * 32, k0 = blockIdx.y * 32;
  int tx = threadIdx.x & 31, ty = threadIdx.x >> 5;  // 32 x 8
  #pragma unroll
  for (int i = 0; i < 32; i += 8) {
    int k = k0 + ty + i, n = n0 + tx;
    t[ty + i][tx] = (k < Kblk && n < Nblk) ? src[(size_t)k * ld_src + n] : 0.0f;
  }
  __syncthreads();
  #pragma unroll
  for (int i = 0; i < 32; i += 8) {
    int n = n0 + ty + i, k = k0 + tx;
    if (n < Nblk && k < Kblk) {
      int R = n + n_off;
      if (mode == 1) {
        int g = R >> 10, h = R & 1023;
        R = (h >> 4) * 80 + g * 16 + (h & 15);
      } else if (mode == 2) {
        int g = R >> 10, h = R & 1023;
        R = (h >> 4) * 64 + g * 16 + (h & 15);
      }
      dst[(size_t)R * lddst + k + k_off] = __float2bfloat16(t[tx][ty + i]);
    }
  }
}

__global__ __launch_bounds__(256) void pack_biases(const float* b_ih1, const float* b_hh1,
                                                   const float* bx, const float* bh,
                                                   const float* b_ih2, const float* b_hh2,
                                                   float* bias_g1, float* bias_g2) {
  int i = blockIdx.x * 256 + threadIdx.x;
  if (i < 4096) {
    bias_g1[i] = b_ih1[i] + b_hh1[i];
    bias_g2[i] = b_ih2[i] + b_hh2[i];
  } else if (i < 5120) {
    bias_g1[i] = bx[i - 4096] + bh[i - 4096];
  }
}

// ------------------------------------------------------- generic bf16 GEMM
struct SegB { const __hip_bfloat16* A; int lda; int kstart; int kend; };
struct GemmBArgs {
  SegB seg[4]; int nseg;
  const __hip_bfloat16* WT; int ldk;
  const float* bias;
  float* C; __hip_bfloat16* C16; int ldc; int N; int Ktot; int act;
};

__global__ __launch_bounds__(256) void gemm_bf16(GemmBArgs ga) {
  __shared__ char lds[65536];  // [buf][A 16K | B 16K]
  const int bm = blockIdx.y * 64;
  const int bn = blockIdx.x * 64;
  const int tid = threadIdx.x;
  const int lane = tid & 63;
  const int w = tid >> 6;
  const int wr = w >> 1, wc = w & 1;

  int rowS[4], scbS[4], dstS[4];
  #pragma unroll
  for (int j = 0; j < 4; ++j) {
    int off = ((j * 4 + w) * 64 + lane) * 16;
    int row = off >> 8, colb = off & 255;
    rowS[j] = row;
    scbS[j] = colb ^ ((row & 7) << 4);
    dstS[j] = (j * 4 + w) * 1024;
  }

  f32x4 acc[2][2] = {};
  const int nit = ga.Ktot >> 7;

  auto stage = [&](int it, int buf) {
    const int k0 = it << 7;
    int si = 0;
    while (k0 >= ga.seg[si].kend) ++si;
    const __hip_bfloat16* Aseg = ga.seg[si].A;
    const int lda = ga.seg[si].lda;
    const int ks = k0 - ga.seg[si].kstart;
    char* baseA = lds + buf * 32768;
    char* baseB = baseA + 16384;
    #pragma unroll
    for (int j = 0; j < 4; ++j) {
      const __hip_bfloat16* sA = Aseg + (size_t)(bm + rowS[j]) * lda + ks + (scbS[j] >> 1);
      __builtin_amdgcn_global_load_lds((AS1C)sA, (AS3P)(baseA + dstS[j]), 16, 0, 0);
      const __hip_bfloat16* sB = ga.WT + (size_t)(bn + rowS[j]) * ga.ldk + k0 + (scbS[j] >> 1);
      __builtin_amdgcn_global_load_lds((AS1C)sB, (AS3P)(baseB + dstS[j]), 16, 0, 0);
    }
  };

  auto compute = [&](int buf) {
    const char* baseA = lds + buf * 32768;
    const char* baseB = baseA + 16384;
    #pragma unroll
    for (int kk = 0; kk < 4; ++kk) {
      bf16x8 a[2], b[2];
      #pragma unroll
      for (int f = 0; f < 2; ++f) {
        int row = wr * 32 + f * 16 + (lane & 15);
        int cb = kk * 64 + (lane >> 4) * 16;
        a[f] = *(const bf16x8*)(baseA + row * 256 + (cb ^ ((row & 7) << 4)));
        int nl = wc * 32 + f * 16 + (lane & 15);
        b[f] = *(const bf16x8*)(baseB + nl * 256 + (cb ^ ((nl & 7) << 4)));
      }
      #pragma unroll
      for (int fm = 0; fm < 2; ++fm)
        #pragma unroll
        for (int fn = 0; fn < 2; ++fn)
          acc[fm][fn] = __builtin_amdgcn_mfma_f32_16x16x32_bf16(a[fm], b[fn], acc[fm][fn], 0, 0, 0);
    }
  };

  stage(0, 0);
  asm volatile("s_waitcnt vmcnt(0)" ::: "memory");
  __builtin_amdgcn_s_barrier();
  for (int it = 0; it < nit - 1; ++it) {
    stage(it + 1, (it & 1) ^ 1);
    compute(it & 1);
    asm volatile("s_waitcnt vmcnt(0)" ::: "memory");
    __builtin_amdgcn_s_barrier();
  }
  compute((nit - 1) & 1);

  #pragma unroll
  for (int fm = 0; fm < 2; ++fm) {
    int rbase = bm + wr * 32 + fm * 16 + (lane >> 4) * 4;
    #pragma unroll
    for (int fn = 0; fn < 2; ++fn) {
      int col = bn + wc * 32 + fn * 16 + (lane & 15);
      if (col >= ga.N) continue;
      float bv = ga.bias ? ga.bias[col] : 0.0f;
      #pragma unroll
      for (int j = 0; j < 4; ++j) {
        float v = acc[fm][fn][j] + bv;
        if (ga.act == 1) v = fmaxf(v, 0.0f);
        size_t off = (size_t)(rbase + j) * ga.ldc + col;
        if (ga.C) ga.C[off] = v;
        if (ga.C16) ga.C16[off] = __float2bfloat16(v);
      }
    }
  }
}

// ------------------------------------------------- gate GEMM + LSTM epilogue
// B is packed so that column-tile j holds all `ngates` gates for h in
// [16j,16j+16): packed_row = (h>>4)*16*ng + gate*16 + (h&15).
// Each wave owns 16 M-rows x all ng fragments -> lane has every gate for one
// h in registers at the epilogue. mode 1: LSTM1+sentinel. mode 2: LSTM2.
struct GateArgs {
  SegB seg[4]; int nseg;
  const __hip_bfloat16* WT;   // packed, ld = 3072
  const float* bias;          // gate-major (unpacked), ng*1024
  int ngates;                 // 5 (g1) or 4 (g2)
  int mode;                   // 1 or 2
  float* cstate;              // c1 or c2 [B][H]
  float* h_out;               // fp32 h1 (mode1) or nullptr
  __hip_bfloat16* hb_out;     // h1b / h2b
  float* st_out;              // st (mode1)
  const float* chat_in;       // (mode2)
  __hip_bfloat16* sbuf_out;   // (mode2)
};

__global__ __launch_bounds__(256) void gemm_gates(GateArgs ga) {
  __shared__ char lds[73728];  // 2 x (A 16K + B up to 20K)
  const int bm = blockIdx.y * 64;
  const int tid = threadIdx.x;
  const int lane = tid & 63;
  const int w = tid >> 6;
  const int ng = ga.ngates;
  const int bsz = 16384 + ng * 4096;
  const int bnp = blockIdx.x * 16 * ng;  // packed B row base for this tile

  f32x4 acc[5] = {};
  const int nit = 3072 >> 7;

  // per-thread staging geometry (row/col within a tile round)
  const int srow = w * 4 + (lane >> 4);          // + r*16
  const int scol = ((lane & 15) * 16);           // linear col byte
  const int sdst = w * 1024 + (lane & 15) * 16 + (lane >> 4) * 256;  // == linear off

  auto stage = [&](int it, int buf) {
    const int k0 = it << 7;
    int si = 0;
    while (k0 >= ga.seg[si].kend) ++si;
    const __hip_bfloat16* Aseg = ga.seg[si].A;
    const int lda = ga.seg[si].lda;
    const int ks = k0 - ga.seg[si].kstart;
    char* baseA = lds + buf * bsz;
    char* baseB = baseA + 16384;
    #pragma unroll
    for (int r = 0; r < 4; ++r) {
      int row = r * 16 + srow;
      int scb = scol ^ ((row & 7) << 4);
      const __hip_bfloat16* sA = Aseg + (size_t)(bm + row) * lda + ks + (scb >> 1);
      __builtin_amdgcn_global_load_lds((AS1C)sA, (AS3P)(baseA + r * 4096 + sdst), 16, 0, 0);
    }
    for (int r = 0; r < ng; ++r) {
      int row = r * 16 + srow;
      int scb = scol ^ ((row & 7) << 4);
      const __hip_bfloat16* sB = ga.WT + (size_t)(bnp + row) * 3072 + k0 + (scb >> 1);
      __builtin_amdgcn_global_load_lds((AS1C)sB, (AS3P)(baseB + r * 4096 + sdst), 16, 0, 0);
    }
  };

  auto compute = [&](int buf) {
    const char* baseA = lds + buf * bsz;
    const char* baseB = baseA + 16384;
    #pragma unroll
    for (int kk = 0; kk < 4; ++kk) {
      int cb = kk * 64 + (lane >> 4) * 16;
      int arow = w * 16 + (lane & 15);
      bf16x8 a = *(const bf16x8*)(baseA + arow * 256 + (cb ^ ((arow & 7) << 4)));
      #pragma unroll
      for (int g = 0; g < 5; ++g) {
        if (g >= ng) break;
        int brow = g * 16 + (lane & 15);
        bf16x8 b = *(const bf16x8*)(baseB + brow * 256 + (cb ^ ((brow & 7) << 4)));
        acc[g] = __builtin_amdgcn_mfma_f32_16x16x32_bf16(a, b, acc[g], 0, 0, 0);
      }
    }
  };

  stage(0, 0);
  asm volatile("s_waitcnt vmcnt(0)" ::: "memory");
  __builtin_amdgcn_s_barrier();
  for (int it = 0; it < nit - 1; ++it) {
    stage(it + 1, (it & 1) ^ 1);
    compute(it & 1);
    asm volatile("s_waitcnt vmcnt(0)" ::: "memory");
    __builtin_amdgcn_s_barrier();
  }
  compute((nit - 1) & 1);

  // ---- epilogue: LSTM cell update in registers
  const int h = blockIdx.x * 16 + (lane & 15);
  const int rbase = bm + w * 16 + (lane >> 4) * 4;
  const float bi = ga.bias[h];
  const float bf = ga.bias[1024 + h];
  const float bg = ga.bias[2048 + h];
  const float bo = ga.bias[3072 + h];
  const float bsen = (ga.mode == 1) ? ga.bias[4096 + h] : 0.0f;
  #pragma unroll
  for (int j = 0; j < 4; ++j) {
    const int idx = (rbase + j) * kH + h;
    float iv = sigf(acc[0][j] + bi);
    float fv = sigf(acc[1][j] + bf);
    float gv = tanhf(acc[2][j] + bg);
    float ov = sigf(acc[3][j] + bo);
    float c = fv * ga.cstate[idx] + iv * gv;
    float tc = tanhf(c);
    float hn = ov * tc;
    ga.cstate[idx] = c;
    ga.hb_out[idx] = __float2bfloat16(hn);
    if (ga.mode == 1) {
      ga.h_out[idx] = hn;
      ga.st_out[idx] = sigf(acc[4][j] + bsen) * tc;
    } else {
      ga.sbuf_out[idx] = __float2bfloat16(ga.chat_in[idx] + hn);
    }
  }
}

// ------------------------------------------------------- small fused kernels
__global__ __launch_bounds__(256) void mean_p(const float* __restrict__ Vfeat,
                                              __hip_bfloat16* __restrict__ meanVb) {
  int idx = blockIdx.x * 256 + threadIdx.x;
  if (idx >= kB * kH) return;
  int b = idx >> 10, h = idx & 1023;
  float sm = 0.0f;
  for (int p = 0; p < kP; ++p) sm += Vfeat[((size_t)b * kP + p) * kH + h];
  meanVb[idx] = __float2bfloat16(sm * (1.0f / kP));
}

__global__ __launch_bounds__(256) void gather_emb(const int* __restrict__ caps,
                                                  const float* __restrict__ emb,
                                                  __hip_bfloat16* __restrict__ wembb) {
  int idx = blockIdx.x * 256 + threadIdx.x;
  if (idx >= kB * kT * kE) return;
  int e = idx % kE;
  int bt = idx / kE;
  int t = bt % kT;
  int b = bt / kT;
  int tok = caps[b * (kT + 1) + t];
  wembb[idx] = __float2bfloat16(emb[(size_t)tok * kE + e]);
}

// Adaptive attention step (attention only; LSTM1 fused into g1 epilogue).
__global__ __launch_bounds__(256) void attn_step(
    const float* __restrict__ h1, const float* __restrict__ st,
    const float* __restrict__ img_proj, const float* __restrict__ Vfeat,
    const float* __restrict__ Wg, const float* __restrict__ Ws,
    const float* __restrict__ bs, const float* __restrict__ wh,
    float* __restrict__ c_hat, __hip_bfloat16* __restrict__ c_hatb,
    float* __restrict__ out_alphas, float* __restrict__ out_betas, int t) {
  const int b = blockIdx.x;
  const int tid = threadIdx.x;
  const int lane = tid & 63;
  const int w = tid >> 6;
  __shared__ float sh_h1[kH];
  __shared__ float sh_st[kH];
  __shared__ float wsum[4][36];
  __shared__ float htp[36];
  __shared__ float stp[36];
  __shared__ float alpha[kP];
  __shared__ float sred[4];  // 0: att_vs, 1: beta, 2: zmax, 3: zsum

  #pragma unroll
  for (int i = 0; i < 4; ++i) {
    int h = tid + i * 256;
    sh_h1[h] = h1[(size_t)b * kH + h];
    sh_st[h] = st[(size_t)b * kH + h];
  }
  __syncthreads();

  // htp = h1 . Wg (pass 0);  stp = st . Ws (pass 1): thread-major partials
  #pragma unroll
  for (int pass = 0; pass < 2; ++pass) {
    const float* vec = pass == 0 ? sh_h1 : sh_st;
    const float* W = pass == 0 ? Wg : Ws;
    float pg[36];
    #pragma unroll
    for (int j = 0; j < 36; ++j) pg[j] = 0.0f;
    #pragma unroll
    for (int i = 0; i < 4; ++i) {
      int hh = tid + i * 256;
      float hv = vec[hh];
      const float4* wrow = reinterpret_cast<const float4*>(W + (size_t)hh * 36);
      #pragma unroll
      for (int r = 0; r < 9; ++r) {
        float4 wv = wrow[r];
        pg[4 * r + 0] = fmaf(hv, wv.x, pg[4 * r + 0]);
        pg[4 * r + 1] = fmaf(hv, wv.y, pg[4 * r + 1]);
        pg[4 * r + 2] = fmaf(hv, wv.z, pg[4 * r + 2]);
        pg[4 * r + 3] = fmaf(hv, wv.w, pg[4 * r + 3]);
      }
    }
    #pragma unroll
    for (int j = 0; j < 36; ++j) {
      float v = pg[j];
      #pragma unroll
      for (int off = 32; off > 0; off >>= 1) v += __shfl_down(v, off, 64);
      if (lane == 0) wsum[w][j] = v;
    }
    __syncthreads();
    if (tid < 36) {
      float s = wsum[0][tid] + wsum[1][tid] + wsum[2][tid] + wsum[3][tid];
      if (pass == 0) htp[tid] = s; else stp[tid] = s;
    }
    __syncthreads();
  }

  if (w == 0) {
    float zz_r = -3.0e38f;
    if (lane < kP) {
      const float* ip = img_proj + ((size_t)b * kP + lane) * kP;
      float acc = 0.0f;
      #pragma unroll
      for (int j = 0; j < kP; ++j) acc = fmaf(tanhf(ip[j] + htp[j]), wh[j], acc);
      zz_r = acc;
    }
    float m = zz_r;
    #pragma unroll
    for (int off = 32; off > 0; off >>= 1) m = fmaxf(m, __shfl_xor(m, off, 64));
    float e = (lane < kP) ? expf(zz_r - m) : 0.0f;
    float s = e;
    #pragma unroll
    for (int off = 32; off > 0; off >>= 1) s += __shfl_xor(s, off, 64);
    if (lane < kP) alpha[lane] = e / s;
    if (lane == 0) { sred[2] = m; sred[3] = s; }
  } else if (w == 1) {
    float tv = 0.0f;
    if (lane < kP) tv = tanhf(stp[lane] + bs[lane] + htp[lane]) * wh[lane];
    #pragma unroll
    for (int off = 32; off > 0; off >>= 1) tv += __shfl_xor(tv, off, 64);
    if (lane == 0) sred[0] = tv;
  }
  __syncthreads();
  if (tid == 0) {
    float av = sred[0], m = sred[2], s = sred[3];
    float m2 = fmaxf(m, av);
    float eb = expf(av - m2);
    float beta = eb / (s * expf(m - m2) + eb);
    sred[1] = beta;
    out_betas[b * kT + t] = beta;
  }
  __syncthreads();
  if (tid < kP) out_alphas[((size_t)b * kT + t) * kP + tid] = alpha[tid];
  const float beta = sred[1];
  #pragma unroll
  for (int i = 0; i < 4; ++i) {
    int h = tid + i * 256;
    float ctx = 0.0f;
    for (int p = 0; p < kP; ++p) ctx = fmaf(alpha[p], Vfeat[((size_t)b * kP + p) * kH + h], ctx);
    float v = beta * sh_st[h] + (1.0f - beta) * ctx;
    c_hat[(size_t)b * kH + h] = v;
    c_hatb[(size_t)b * kH + h] = __float2bfloat16(v);
  }
}

// ------------------------------------------------------------------ launch
extern "C" void kernel_launch(void* const* d_in, const int* in_sizes, int n_in,
                              void* d_out, int out_size, void* d_ws, size_t ws_size,
                              hipStream_t stream) {
  const float* images  = (const float*)d_in[0];
  const int*   caps    = (const int*)d_in[1];
  const float* W_img   = (const float*)d_in[3];
  const float* b_img   = (const float*)d_in[4];
  const float* W_glob  = (const float*)d_in[5];
  const float* b_glob  = (const float*)d_in[6];
  const float* W_ih1   = (const float*)d_in[7];
  const float* W_hh1   = (const float*)d_in[8];
  const float* b_ih1   = (const float*)d_in[9];
  const float* b_hh1   = (const float*)d_in[10];
  const float* Wx_gate = (const float*)d_in[11];
  const float* bx_gate = (const float*)d_in[12];
  const float* Wh_gate = (const float*)d_in[13];
  const float* bh_gate = (const float*)d_in[14];
  const float* W_ih2   = (const float*)d_in[15];
  const float* W_hh2   = (const float*)d_in[16];
  const float* b_ih2   = (const float*)d_in[17];
  const float* b_hh2   = (const float*)d_in[18];
  const float* Wv      = (const float*)d_in[19];
  const float* bv      = (const float*)d_in[20];
  const float* Ws_     = (const float*)d_in[21];
  const float* bs_     = (const float*)d_in[22];
  const float* Wg      = (const float*)d_in[23];
  const float* wh      = (const float*)d_in[24];
  const float* emb     = (const float*)d_in[25];
  const float* W_fc    = (const float*)d_in[26];
  const float* b_fc    = (const float*)d_in[27];

  float* out = (float*)d_out;
  float* out_alphas = out + (size_t)kB * kT * kV;
  float* out_betas  = out_alphas + (size_t)kB * kT * kP;

  char* base = (char*)d_ws;
  auto alloc = [&](size_t bytes) {
    char* p = base;
    base += (bytes + 255) & ~(size_t)255;
    return p;
  };
  float*          Vfeat   = (float*)alloc((size_t)kB * kP * kH * 4);
  __hip_bfloat16* Vfeatb  = (__hip_bfloat16*)alloc((size_t)kB * kP * kH * 2);
  __hip_bfloat16* imagesb = (__hip_bfloat16*)alloc((size_t)kB * kP * kRaw * 2);
  __hip_bfloat16* WTg1    = (__hip_bfloat16*)alloc((size_t)5120 * 3072 * 2);
  __hip_bfloat16* WTg2    = (__hip_bfloat16*)alloc((size_t)4096 * 3072 * 2);
  __hip_bfloat16* WTfc    = (__hip_bfloat16*)alloc((size_t)12032 * 1024 * 2);
  __hip_bfloat16* WTimg   = (__hip_bfloat16*)alloc((size_t)1024 * 2048 * 2);
  __hip_bfloat16* WTglob  = (__hip_bfloat16*)alloc((size_t)512 * 1024 * 2);
  __hip_bfloat16* WTv     = (__hip_bfloat16*)alloc((size_t)64 * 1024 * 2);
  __hip_bfloat16* wembb   = (__hip_bfloat16*)alloc((size_t)kB * kT * kE * 2);
  float*          img_proj= (float*)alloc((size_t)kB * kP * kP * 4);
  __hip_bfloat16* globb   = (__hip_bfloat16*)alloc((size_t)kB * kE * 2);
  __hip_bfloat16* meanVb  = (__hip_bfloat16*)alloc((size_t)kB * kH * 2);
  float*          c1      = (float*)alloc((size_t)2 * kB * kH * 4);  // c1, c2
  float*          c2      = c1 + kB * kH;
  __hip_bfloat16* h1b     = (__hip_bfloat16*)alloc((size_t)2 * kB * kH * 2);
  __hip_bfloat16* h2b     = h1b + kB * kH;
  float*          h1f     = (float*)alloc((size_t)kB * kH * 4);
  float*          st      = (float*)alloc((size_t)kB * kH * 4);
  float*          chat    = (float*)alloc((size_t)kB * kH * 4);
  __hip_bfloat16* chatb   = (__hip_bfloat16*)alloc((size_t)kB * kH * 2);
  __hip_bfloat16* sbufb   = (__hip_bfloat16*)alloc((size_t)kB * kH * 2);
  float*          bias_g1 = (float*)alloc(5120 * 4);
  float*          bias_g2 = (float*)alloc(4096 * 4);

  // ---- once-per-call prep
  zero_f32<<<(2 * kB * kH + 255) / 256, 256, 0, stream>>>(c1, 2 * kB * kH);
  zero_bf16<<<(2 * kB * kH + 255) / 256, 256, 0, stream>>>(h1b, 2 * kB * kH);
  {
    int n4 = kB * kP * kRaw / 4;
    f32_to_bf16<<<(n4 + 255) / 256, 256, 0, stream>>>(images, imagesb, n4);
  }
  auto T = [&](const float* src, int ldsrc, int K, int N, __hip_bfloat16* dst, int lddst,
               int koff, int noff, int mode) {
    transpose_to_bf16<<<dim3((N + 31) / 32, (K + 31) / 32), 256, 0, stream>>>(
        src, ldsrc, K, N, dst, lddst, koff, noff, mode);
  };
  T(W_img,   kH,     kRaw, kH,     WTimg,  kRaw, 0, 0, 0);
  T(W_glob,  kE,     kH,   kE,     WTglob, kH,   0, 0, 0);
  zero_bf16<<<(64 * 1024 + 255) / 256, 256, 0, stream>>>(WTv, 64 * 1024);
  T(Wv,      kP,     kH,   kP,     WTv,    kH,   0, 0, 0);
  T(W_ih1,   4 * kH, 2048, 4 * kH, WTg1,   3072, 0, 0, 1);
  T(W_hh1,   4 * kH, 1024, 4 * kH, WTg1,   3072, 2048, 0, 1);
  T(Wx_gate, kH,     2048, kH,     WTg1,   3072, 0, 4096, 1);
  T(Wh_gate, kH,     1024, kH,     WTg1,   3072, 2048, 4096, 1);
  T(W_ih2,   4 * kH, 2048, 4 * kH, WTg2,   3072, 0, 0, 2);
  T(W_hh2,   4 * kH, 1024, 4 * kH, WTg2,   3072, 2048, 0, 2);
  T(W_fc,    kV,     kH,   kV,     WTfc,   kH,   0, 0, 0);
  zero_bf16<<<(32 * 1024 + 255) / 256, 256, 0, stream>>>(WTfc + (size_t)12000 * 1024, 32 * 1024);
  pack_biases<<<20, 256, 0, stream>>>(b_ih1, b_hh1, bx_gate, bh_gate, b_ih2, b_hh2,
                                      bias_g1, bias_g2);
  gather_emb<<<(kB * kT * kE + 255) / 256, 256, 0, stream>>>(caps, emb, wembb);

  // Vfeat = relu(images @ W_img + b_img)   [4608 x 1024], K=2048
  {
    GemmBArgs ga = {};
    ga.seg[0] = {imagesb, kRaw, 0, kRaw};
    ga.nseg = 1; ga.WT = WTimg; ga.ldk = kRaw; ga.bias = b_img;
    ga.C = Vfeat; ga.C16 = Vfeatb; ga.ldc = kH; ga.N = kH; ga.Ktot = kRaw; ga.act = 1;
    gemm_bf16<<<dim3(kH / 64, kB * kP / 64), 256, 0, stream>>>(ga);
  }
  mean_p<<<(kB * kH + 255) / 256, 256, 0, stream>>>(Vfeat, meanVb);
  // glob = relu(meanV @ W_glob + b_glob)
  {
    GemmBArgs ga = {};
    ga.seg[0] = {meanVb, kH, 0, kH};
    ga.nseg = 1; ga.WT = WTglob; ga.ldk = kH; ga.bias = b_glob;
    ga.C = nullptr; ga.C16 = globb; ga.ldc = kE; ga.N = kE; ga.Ktot = kH; ga.act = 1;
    gemm_bf16<<<dim3(kE / 64, kB / 64), 256, 0, stream>>>(ga);
  }
  // img_proj = Vfeat @ Wv + bv
  {
    GemmBArgs ga = {};
    ga.seg[0] = {Vfeatb, kH, 0, kH};
    ga.nseg = 1; ga.WT = WTv; ga.ldk = kH; ga.bias = bv;
    ga.C = img_proj; ga.C16 = nullptr; ga.ldc = kP; ga.N = kP; ga.Ktot = kH; ga.act = 0;
    gemm_bf16<<<dim3(1, kB * kP / 64), 256, 0, stream>>>(ga);
  }

  // ---- 20 decode steps (4 kernels each)
  for (int t = 0; t < kT; ++t) {
    {  // g1 + sentinel GEMM + LSTM1 epilogue
      GateArgs ga = {};
      ga.seg[0] = {h2b, kH, 0, kH};
      ga.seg[1] = {globb, kE, kH, kH + kE};
      ga.seg[2] = {wembb + (size_t)t * kE, kT * kE, kH + kE, 2048};
      ga.seg[3] = {h1b, kH, 2048, 3072};
      ga.nseg = 4; ga.WT = WTg1; ga.bias = bias_g1;
      ga.ngates = 5; ga.mode = 1;
      ga.cstate = c1; ga.h_out = h1f; ga.hb_out = h1b; ga.st_out = st;
      gemm_gates<<<dim3(64, 2), 256, 0, stream>>>(ga);
    }
    attn_step<<<kB, 256, 0, stream>>>(h1f, st, img_proj, Vfeat, Wg, Ws_, bs_, wh,
                                      chat, chatb, out_alphas, out_betas, t);
    {  // g2 GEMM + LSTM2 epilogue
      GateArgs ga = {};
      ga.seg[0] = {chatb, kH, 0, kH};
      ga.seg[1] = {h1b, kH, kH, 2048};
      ga.seg[2] = {h2b, kH, 2048, 3072};
      ga.nseg = 3; ga.WT = WTg2; ga.bias = bias_g2;
      ga.ngates = 4; ga.mode = 2;
      ga.cstate = c2; ga.hb_out = h2b; ga.chat_in = chat; ga.sbuf_out = sbufb;
      gemm_gates<<<dim3(64, 2), 256, 0, stream>>>(ga);
    }
    {  // fc: [128 x 12000], K = 1024
      GemmBArgs ga = {};
      ga.seg[0] = {sbufb, kH, 0, kH};
      ga.nseg = 1; ga.WT = WTfc; ga.ldk = kH; ga.bias = b_fc;
      ga.C = out + (size_t)t * kV; ga.C16 = nullptr; ga.ldc = kT * kV; ga.N = kV; ga.Ktot = kH; ga.act = 0;
      gemm_bf16<<<dim3(12032 / 64, kB / 64), 256, 0, stream>>>(ga);
    }
  }
}

// Round 6
// 1917.045 us; speedup vs baseline: 1.1641x; 1.1641x over previous
//
#include <hip/hip_runtime.h>
#include <hip/hip_bf16.h>
#include <math.h>

typedef __attribute__((ext_vector_type(4))) float f32x4;
typedef __attribute__((ext_vector_type(8))) short bf16x8;

constexpr int kB = 128, kT = 20, kH = 1024, kE = 512, kP = 36, kRaw = 2048, kV = 12000;

__device__ __forceinline__ float sigf(float x) { return 1.0f / (1.0f + expf(-x)); }

#define AS1C const __attribute__((address_space(1))) void*
#define AS3P __attribute__((address_space(3))) void*

// ---------------------------------------------------------------- utilities
__global__ __launch_bounds__(256) void zero_f32(float* p, int n) {
  int i = blockIdx.x * 256 + threadIdx.x;
  if (i < n) p[i] = 0.0f;
}
__global__ __launch_bounds__(256) void zero_bf16(__hip_bfloat16* p, int n) {
  int i = blockIdx.x * 256 + threadIdx.x;
  if (i < n) p[i] = __float2bfloat16(0.0f);
}
__global__ __launch_bounds__(256) void f32_to_bf16(const float* __restrict__ src,
                                                   __hip_bfloat16* __restrict__ dst, int n4) {
  int i = blockIdx.x * 256 + threadIdx.x;
  if (i >= n4) return;
  float4 v = reinterpret_cast<const float4*>(src)[i];
  __hip_bfloat16* d = dst + (size_t)i * 4;
  d[0] = __float2bfloat16(v.x); d[1] = __float2bfloat16(v.y);
  d[2] = __float2bfloat16(v.z); d[3] = __float2bfloat16(v.w);
}

// dst[n + n_off][k + k_off] = bf16(src[k][n]);  src is [Kblk][ld_src]
__global__ __launch_bounds__(256) void transpose_to_bf16(const float* __restrict__ src, int ld_src,
                                                         int Kblk, int Nblk,
                                                         __hip_bfloat16* __restrict__ dst, int lddst,
                                                         int k_off, int n_off) {
  __shared__ float t[32][33];
  int n0 = blockIdx.x * 32, k0 = blockIdx.y * 32;
  int tx = threadIdx.x & 31, ty = threadIdx.x >> 5;  // 32 x 8
  #pragma unroll
  for (int i = 0; i < 32; i += 8) {
    int k = k0 + ty + i, n = n0 + tx;
    t[ty + i][tx] = (k < Kblk && n < Nblk) ? src[(size_t)k * ld_src + n] : 0.0f;
  }
  __syncthreads();
  #pragma unroll
  for (int i = 0; i < 32; i += 8) {
    int n = n0 + ty + i, k = k0 + tx;
    if (n < Nblk && k < Kblk)
      dst[(size_t)(n + n_off) * lddst + k + k_off] = __float2bfloat16(t[tx][ty + i]);
  }
}

__global__ __launch_bounds__(256) void pack_biases(const float* b_ih1, const float* b_hh1,
                                                   const float* bx, const float* bh,
                                                   const float* b_ih2, const float* b_hh2,
                                                   float* bias_g1, float* bias_g2) {
  int i = blockIdx.x * 256 + threadIdx.x;
  if (i < 4096) {
    bias_g1[i] = b_ih1[i] + b_hh1[i];
    bias_g2[i] = b_ih2[i] + b_hh2[i];
  } else if (i < 5120) {
    bias_g1[i] = bx[i - 4096] + bh[i - 4096];
  }
}

// ------------------------------------------------------- bf16 MFMA GEMM
// C[M,N] = act( concat_K(A_segs) @ WT^T + bias ), WT is [N][K] bf16.
// BM=BN=64, BK=128. 3-buffer LDS pipeline with COUNTED vmcnt (T4): stage
// tile t+2, compute t, then wait vmcnt(8) -> only t+1's loads must land;
// t+2's 8 stay in flight across the barrier. Requires nit >= 2.
// cmap==1: row m -> out[(m&127)*ldc + (m>>7)*kV] (batched-fc remap).
struct SegB { const __hip_bfloat16* A; int lda; int kstart; int kend; };
struct GemmBArgs {
  SegB seg[4]; int nseg;
  const __hip_bfloat16* WT; int ldk;
  const float* bias;
  float* C; __hip_bfloat16* C16; int ldc; int N; int Ktot; int act; int cmap;
};

__global__ __launch_bounds__(256) void gemm_bf16(GemmBArgs ga) {
  __shared__ char lds[98304];  // 3 bufs x (A 16K | B 16K)
  const int bm = blockIdx.y * 64;
  const int bn = blockIdx.x * 64;
  const int tid = threadIdx.x;
  const int lane = tid & 63;
  const int w = tid >> 6;
  const int wr = w >> 1, wc = w & 1;

  int rowS[4], scbS[4], dstS[4];
  #pragma unroll
  for (int j = 0; j < 4; ++j) {
    int off = ((j * 4 + w) * 64 + lane) * 16;   // linear byte in 16 KB tile
    int row = off >> 8, colb = off & 255;       // row stride 256 B (BK=128 bf16)
    rowS[j] = row;
    scbS[j] = colb ^ ((row & 7) << 4);
    dstS[j] = (j * 4 + w) * 1024;
  }

  f32x4 acc[2][2] = {};
  const int nit = ga.Ktot >> 7;

  auto stage = [&](int it, int buf) {
    const int k0 = it << 7;
    int si = 0;
    while (k0 >= ga.seg[si].kend) ++si;
    const __hip_bfloat16* Aseg = ga.seg[si].A;
    const int lda = ga.seg[si].lda;
    const int ks = k0 - ga.seg[si].kstart;
    char* baseA = lds + buf * 32768;
    char* baseB = baseA + 16384;
    #pragma unroll
    for (int j = 0; j < 4; ++j) {
      const __hip_bfloat16* sA = Aseg + (size_t)(bm + rowS[j]) * lda + ks + (scbS[j] >> 1);
      __builtin_amdgcn_global_load_lds((AS1C)sA, (AS3P)(baseA + dstS[j]), 16, 0, 0);
      const __hip_bfloat16* sB = ga.WT + (size_t)(bn + rowS[j]) * ga.ldk + k0 + (scbS[j] >> 1);
      __builtin_amdgcn_global_load_lds((AS1C)sB, (AS3P)(baseB + dstS[j]), 16, 0, 0);
    }
  };

  auto compute = [&](int buf) {
    const char* baseA = lds + buf * 32768;
    const char* baseB = baseA + 16384;
    #pragma unroll
    for (int kk = 0; kk < 4; ++kk) {
      bf16x8 a[2], b[2];
      #pragma unroll
      for (int f = 0; f < 2; ++f) {
        int row = wr * 32 + f * 16 + (lane & 15);
        int cb = kk * 64 + (lane >> 4) * 16;
        a[f] = *(const bf16x8*)(baseA + row * 256 + (cb ^ ((row & 7) << 4)));
        int nl = wc * 32 + f * 16 + (lane & 15);
        b[f] = *(const bf16x8*)(baseB + nl * 256 + (cb ^ ((nl & 7) << 4)));
      }
      #pragma unroll
      for (int fm = 0; fm < 2; ++fm)
        #pragma unroll
        for (int fn = 0; fn < 2; ++fn)
          acc[fm][fn] = __builtin_amdgcn_mfma_f32_16x16x32_bf16(a[fm], b[fn], acc[fm][fn], 0, 0, 0);
    }
  };

  // prologue: fill bufs 0 and 1; wait only for buf0 (8 of buf1 outstanding)
  stage(0, 0);
  stage(1, 1);
  asm volatile("s_waitcnt vmcnt(8)" ::: "memory");
  __builtin_amdgcn_s_barrier();
  int cbuf = 0;
  for (int it = 0; it < nit; ++it) {
    if (it + 2 < nit) {
      int sb = cbuf + 2; if (sb >= 3) sb -= 3;
      stage(it + 2, sb);
    }
    compute(cbuf);
    if (it + 1 < nit) {
      if (it + 2 < nit) asm volatile("s_waitcnt vmcnt(8)" ::: "memory");
      else              asm volatile("s_waitcnt vmcnt(0)" ::: "memory");
      __builtin_amdgcn_s_barrier();
    }
    ++cbuf; if (cbuf == 3) cbuf = 0;
  }

  #pragma unroll
  for (int fm = 0; fm < 2; ++fm) {
    int rbase = bm + wr * 32 + fm * 16 + (lane >> 4) * 4;
    #pragma unroll
    for (int fn = 0; fn < 2; ++fn) {
      int col = bn + wc * 32 + fn * 16 + (lane & 15);
      if (col >= ga.N) continue;
      float bv = ga.bias ? ga.bias[col] : 0.0f;
      #pragma unroll
      for (int j = 0; j < 4; ++j) {
        float v = acc[fm][fn][j] + bv;
        if (ga.act == 1) v = fmaxf(v, 0.0f);
        int m = rbase + j;
        size_t off = ga.cmap == 1
            ? (size_t)(m & 127) * ga.ldc + (size_t)(m >> 7) * kV + col
            : (size_t)m * ga.ldc + col;
        if (ga.C) ga.C[off] = v;
        if (ga.C16) ga.C16[off] = __float2bfloat16(v);
      }
    }
  }
}

// ------------------------------------------------------- small fused kernels
__global__ __launch_bounds__(256) void mean_p(const float* __restrict__ Vfeat,
                                              __hip_bfloat16* __restrict__ meanVb) {
  int idx = blockIdx.x * 256 + threadIdx.x;
  if (idx >= kB * kH) return;
  int b = idx >> 10, h = idx & 1023;
  float sm = 0.0f;
  for (int p = 0; p < kP; ++p) sm += Vfeat[((size_t)b * kP + p) * kH + h];
  meanVb[idx] = __float2bfloat16(sm * (1.0f / kP));
}

__global__ __launch_bounds__(256) void gather_emb(const int* __restrict__ caps,
                                                  const float* __restrict__ emb,
                                                  __hip_bfloat16* __restrict__ wembb) {
  int idx = blockIdx.x * 256 + threadIdx.x;
  if (idx >= kB * kT * kE) return;
  int e = idx % kE;
  int bt = idx / kE;
  int t = bt % kT;
  int b = bt / kT;
  int tok = caps[b * (kT + 1) + t];
  wembb[idx] = __float2bfloat16(emb[(size_t)tok * kE + e]);
}

// LSTM1 gates + sentinel + full adaptive-attention step. One block per batch
// element. htp/stp computed thread-major (coalesced Wg/Ws rows, 36 register
// accumulators) + wave shuffle reduce; softmax wave-parallel.
__global__ __launch_bounds__(256) void step1_fused(
    const float* __restrict__ g, float* __restrict__ c1,
    __hip_bfloat16* __restrict__ h1b,
    const float* __restrict__ img_proj, const float* __restrict__ Vfeat,
    const float* __restrict__ Wg, const float* __restrict__ Ws,
    const float* __restrict__ bs, const float* __restrict__ wh,
    float* __restrict__ c_hat, __hip_bfloat16* __restrict__ c_hatb,
    float* __restrict__ out_alphas, float* __restrict__ out_betas, int t) {
  const int b = blockIdx.x;
  const int tid = threadIdx.x;
  const int lane = tid & 63;
  const int w = tid >> 6;
  __shared__ float sh_h1[kH];
  __shared__ float sh_st[kH];
  __shared__ float wsum[4][36];
  __shared__ float htp[36];
  __shared__ float stp[36];
  __shared__ float alpha[kP];
  __shared__ float sred[4];  // 0: att_vs, 1: beta, 2: zmax, 3: zsum

  // ---- LSTM1 gates + sentinel
  const float* gr = g + (size_t)b * 5120;
  #pragma unroll
  for (int i = 0; i < 4; ++i) {
    int h = tid + i * 256;
    float ig = sigf(gr[h]);
    float fg = sigf(gr[kH + h]);
    float gg = tanhf(gr[2 * kH + h]);
    float og = sigf(gr[3 * kH + h]);
    int idx = b * kH + h;
    float c = fg * c1[idx] + ig * gg;
    float tc = tanhf(c);
    float hn = og * tc;
    c1[idx] = c;
    h1b[idx] = __float2bfloat16(hn);
    sh_h1[h] = hn;
    sh_st[h] = sigf(gr[4 * kH + h]) * tc;
  }
  __syncthreads();

  // ---- htp = h1 . Wg (pass 0);  stp = st . Ws (pass 1)
  #pragma unroll
  for (int pass = 0; pass < 2; ++pass) {
    const float* vec = pass == 0 ? sh_h1 : sh_st;
    const float* W = pass == 0 ? Wg : Ws;
    float pg[36];
    #pragma unroll
    for (int j = 0; j < 36; ++j) pg[j] = 0.0f;
    #pragma unroll
    for (int i = 0; i < 4; ++i) {
      int hh = tid + i * 256;
      float hv = vec[hh];
      const float4* wrow = reinterpret_cast<const float4*>(W + (size_t)hh * 36);
      #pragma unroll
      for (int r = 0; r < 9; ++r) {
        float4 wv = wrow[r];
        pg[4 * r + 0] = fmaf(hv, wv.x, pg[4 * r + 0]);
        pg[4 * r + 1] = fmaf(hv, wv.y, pg[4 * r + 1]);
        pg[4 * r + 2] = fmaf(hv, wv.z, pg[4 * r + 2]);
        pg[4 * r + 3] = fmaf(hv, wv.w, pg[4 * r + 3]);
      }
    }
    #pragma unroll
    for (int j = 0; j < 36; ++j) {
      float v = pg[j];
      #pragma unroll
      for (int off = 32; off > 0; off >>= 1) v += __shfl_down(v, off, 64);
      if (lane == 0) wsum[w][j] = v;
    }
    __syncthreads();
    if (tid < 36) {
      float s = wsum[0][tid] + wsum[1][tid] + wsum[2][tid] + wsum[3][tid];
      if (pass == 0) htp[tid] = s; else stp[tid] = s;
    }
    __syncthreads();
  }

  if (w == 0) {
    float zz_r = -3.0e38f;
    if (lane < kP) {
      const float* ip = img_proj + ((size_t)b * kP + lane) * kP;
      float acc = 0.0f;
      #pragma unroll
      for (int j = 0; j < kP; ++j) acc = fmaf(tanhf(ip[j] + htp[j]), wh[j], acc);
      zz_r = acc;
    }
    float m = zz_r;
    #pragma unroll
    for (int off = 32; off > 0; off >>= 1) m = fmaxf(m, __shfl_xor(m, off, 64));
    float e = (lane < kP) ? expf(zz_r - m) : 0.0f;
    float s = e;
    #pragma unroll
    for (int off = 32; off > 0; off >>= 1) s += __shfl_xor(s, off, 64);
    if (lane < kP) alpha[lane] = e / s;
    if (lane == 0) { sred[2] = m; sred[3] = s; }
  } else if (w == 1) {
    float tv = 0.0f;
    if (lane < kP) tv = tanhf(stp[lane] + bs[lane] + htp[lane]) * wh[lane];
    #pragma unroll
    for (int off = 32; off > 0; off >>= 1) tv += __shfl_xor(tv, off, 64);
    if (lane == 0) sred[0] = tv;
  }
  __syncthreads();
  if (tid == 0) {
    float av = sred[0], m = sred[2], s = sred[3];
    float m2 = fmaxf(m, av);
    float eb = expf(av - m2);
    float beta = eb / (s * expf(m - m2) + eb);
    sred[1] = beta;
    out_betas[b * kT + t] = beta;
  }
  __syncthreads();
  if (tid < kP) out_alphas[((size_t)b * kT + t) * kP + tid] = alpha[tid];
  const float beta = sred[1];
  #pragma unroll
  for (int i = 0; i < 4; ++i) {
    int h = tid + i * 256;
    float ctx = 0.0f;
    for (int p = 0; p < kP; ++p) ctx = fmaf(alpha[p], Vfeat[((size_t)b * kP + p) * kH + h], ctx);
    float v = beta * sh_st[h] + (1.0f - beta) * ctx;
    c_hat[(size_t)b * kH + h] = v;
    c_hatb[(size_t)b * kH + h] = __float2bfloat16(v);
  }
}

// g layout: [b][4096]; sbufb points at this step's [B][H] slice.
__global__ __launch_bounds__(256) void lstm2_elem(const float* __restrict__ g,
                                                  float* __restrict__ c2,
                                                  __hip_bfloat16* __restrict__ h2b,
                                                  const float* __restrict__ c_hat,
                                                  __hip_bfloat16* __restrict__ sbufb) {
  int idx = blockIdx.x * 256 + threadIdx.x;
  if (idx >= kB * kH) return;
  int b = idx >> 10, h = idx & 1023;
  const float* gr = g + (size_t)b * 4 * kH;
  float ig = sigf(gr[h]);
  float fg = sigf(gr[kH + h]);
  float gg = tanhf(gr[2 * kH + h]);
  float og = sigf(gr[3 * kH + h]);
  float c = fg * c2[idx] + ig * gg;
  float hn = og * tanhf(c);
  c2[idx] = c;
  h2b[idx] = __float2bfloat16(hn);
  sbufb[idx] = __float2bfloat16(c_hat[idx] + hn);
}

// ------------------------------------------------------------------ launch
extern "C" void kernel_launch(void* const* d_in, const int* in_sizes, int n_in,
                              void* d_out, int out_size, void* d_ws, size_t ws_size,
                              hipStream_t stream) {
  const float* images  = (const float*)d_in[0];
  const int*   caps    = (const int*)d_in[1];
  const float* W_img   = (const float*)d_in[3];
  const float* b_img   = (const float*)d_in[4];
  const float* W_glob  = (const float*)d_in[5];
  const float* b_glob  = (const float*)d_in[6];
  const float* W_ih1   = (const float*)d_in[7];
  const float* W_hh1   = (const float*)d_in[8];
  const float* b_ih1   = (const float*)d_in[9];
  const float* b_hh1   = (const float*)d_in[10];
  const float* Wx_gate = (const float*)d_in[11];
  const float* bx_gate = (const float*)d_in[12];
  const float* Wh_gate = (const float*)d_in[13];
  const float* bh_gate = (const float*)d_in[14];
  const float* W_ih2   = (const float*)d_in[15];
  const float* W_hh2   = (const float*)d_in[16];
  const float* b_ih2   = (const float*)d_in[17];
  const float* b_hh2   = (const float*)d_in[18];
  const float* Wv      = (const float*)d_in[19];
  const float* bv      = (const float*)d_in[20];
  const float* Ws_     = (const float*)d_in[21];
  const float* bs_     = (const float*)d_in[22];
  const float* Wg      = (const float*)d_in[23];
  const float* wh      = (const float*)d_in[24];
  const float* emb     = (const float*)d_in[25];
  const float* W_fc    = (const float*)d_in[26];
  const float* b_fc    = (const float*)d_in[27];

  float* out = (float*)d_out;
  float* out_alphas = out + (size_t)kB * kT * kV;
  float* out_betas  = out_alphas + (size_t)kB * kT * kP;

  char* base = (char*)d_ws;
  auto alloc = [&](size_t bytes) {
    char* p = base;
    base += (bytes + 255) & ~(size_t)255;
    return p;
  };
  float*          Vfeat   = (float*)alloc((size_t)kB * kP * kH * 4);
  __hip_bfloat16* Vfeatb  = (__hip_bfloat16*)alloc((size_t)kB * kP * kH * 2);
  __hip_bfloat16* imagesb = (__hip_bfloat16*)alloc((size_t)kB * kP * kRaw * 2);
  __hip_bfloat16* WTg1    = (__hip_bfloat16*)alloc((size_t)5120 * 3072 * 2);
  __hip_bfloat16* WTg2    = (__hip_bfloat16*)alloc((size_t)4096 * 3072 * 2);
  __hip_bfloat16* WTfc    = (__hip_bfloat16*)alloc((size_t)12032 * 1024 * 2);
  __hip_bfloat16* WTimg   = (__hip_bfloat16*)alloc((size_t)1024 * 2048 * 2);
  __hip_bfloat16* WTglob  = (__hip_bfloat16*)alloc((size_t)512 * 1024 * 2);
  __hip_bfloat16* WTv     = (__hip_bfloat16*)alloc((size_t)64 * 1024 * 2);
  __hip_bfloat16* wembb   = (__hip_bfloat16*)alloc((size_t)kB * kT * kE * 2);
  float*          img_proj= (float*)alloc((size_t)kB * kP * kP * 4);
  __hip_bfloat16* globb   = (__hip_bfloat16*)alloc((size_t)kB * kE * 2);
  __hip_bfloat16* meanVb  = (__hip_bfloat16*)alloc((size_t)kB * kH * 2);
  float*          c1      = (float*)alloc((size_t)2 * kB * kH * 4);  // c1, c2
  float*          c2      = c1 + kB * kH;
  __hip_bfloat16* h1b     = (__hip_bfloat16*)alloc((size_t)2 * kB * kH * 2);
  __hip_bfloat16* h2b     = h1b + kB * kH;
  float*          g1out   = (float*)alloc((size_t)kB * 5120 * 4);
  float*          chat    = (float*)alloc((size_t)kB * kH * 4);
  __hip_bfloat16* chatb   = (__hip_bfloat16*)alloc((size_t)kB * kH * 2);
  __hip_bfloat16* sbufall = (__hip_bfloat16*)alloc((size_t)kT * kB * kH * 2);  // [t][b][h]
  float*          bias_g1 = (float*)alloc(5120 * 4);
  float*          bias_g2 = (float*)alloc(4096 * 4);

  // ---- once-per-call prep
  zero_f32<<<(2 * kB * kH + 255) / 256, 256, 0, stream>>>(c1, 2 * kB * kH);
  zero_bf16<<<(2 * kB * kH + 255) / 256, 256, 0, stream>>>(h1b, 2 * kB * kH);
  {
    int n4 = kB * kP * kRaw / 4;
    f32_to_bf16<<<(n4 + 255) / 256, 256, 0, stream>>>(images, imagesb, n4);
  }
  auto T = [&](const float* src, int ldsrc, int K, int N, __hip_bfloat16* dst, int lddst,
               int koff, int noff) {
    transpose_to_bf16<<<dim3((N + 31) / 32, (K + 31) / 32), 256, 0, stream>>>(
        src, ldsrc, K, N, dst, lddst, koff, noff);
  };
  T(W_img,   kH,     kRaw, kH,     WTimg,  kRaw, 0, 0);
  T(W_glob,  kE,     kH,   kE,     WTglob, kH,   0, 0);
  zero_bf16<<<(64 * 1024 + 255) / 256, 256, 0, stream>>>(WTv, 64 * 1024);
  T(Wv,      kP,     kH,   kP,     WTv,    kH,   0, 0);
  T(W_ih1,   4 * kH, 2048, 4 * kH, WTg1,   3072, 0, 0);
  T(W_hh1,   4 * kH, 1024, 4 * kH, WTg1,   3072, 2048, 0);
  T(Wx_gate, kH,     2048, kH,     WTg1,   3072, 0, 4096);
  T(Wh_gate, kH,     1024, kH,     WTg1,   3072, 2048, 4096);
  T(W_ih2,   4 * kH, 2048, 4 * kH, WTg2,   3072, 0, 0);
  T(W_hh2,   4 * kH, 1024, 4 * kH, WTg2,   3072, 2048, 0);
  T(W_fc,    kV,     kH,   kV,     WTfc,   kH,   0, 0);
  zero_bf16<<<(32 * 1024 + 255) / 256, 256, 0, stream>>>(WTfc + (size_t)12000 * 1024, 32 * 1024);
  pack_biases<<<20, 256, 0, stream>>>(b_ih1, b_hh1, bx_gate, bh_gate, b_ih2, b_hh2,
                                      bias_g1, bias_g2);
  gather_emb<<<(kB * kT * kE + 255) / 256, 256, 0, stream>>>(caps, emb, wembb);

  // Vfeat = relu(images @ W_img + b_img)   [4608 x 1024], K=2048
  {
    GemmBArgs ga = {};
    ga.seg[0] = {imagesb, kRaw, 0, kRaw};
    ga.nseg = 1; ga.WT = WTimg; ga.ldk = kRaw; ga.bias = b_img;
    ga.C = Vfeat; ga.C16 = Vfeatb; ga.ldc = kH; ga.N = kH; ga.Ktot = kRaw; ga.act = 1;
    gemm_bf16<<<dim3(kH / 64, kB * kP / 64), 256, 0, stream>>>(ga);
  }
  mean_p<<<(kB * kH + 255) / 256, 256, 0, stream>>>(Vfeat, meanVb);
  // glob = relu(meanV @ W_glob + b_glob)
  {
    GemmBArgs ga = {};
    ga.seg[0] = {meanVb, kH, 0, kH};
    ga.nseg = 1; ga.WT = WTglob; ga.ldk = kH; ga.bias = b_glob;
    ga.C = nullptr; ga.C16 = globb; ga.ldc = kE; ga.N = kE; ga.Ktot = kH; ga.act = 1;
    gemm_bf16<<<dim3(kE / 64, kB / 64), 256, 0, stream>>>(ga);
  }
  // img_proj = Vfeat @ Wv + bv
  {
    GemmBArgs ga = {};
    ga.seg[0] = {Vfeatb, kH, 0, kH};
    ga.nseg = 1; ga.WT = WTv; ga.ldk = kH; ga.bias = bv;
    ga.C = img_proj; ga.C16 = nullptr; ga.ldc = kP; ga.N = kP; ga.Ktot = kH; ga.act = 0;
    gemm_bf16<<<dim3(1, kB * kP / 64), 256, 0, stream>>>(ga);
  }

  // ---- 20 decode steps (4 kernels each; fc deferred)
  for (int t = 0; t < kT; ++t) {
    {  // g1 + sentinel: [128 x 5120], K = 3072
      GemmBArgs ga = {};
      ga.seg[0] = {h2b, kH, 0, kH};
      ga.seg[1] = {globb, kE, kH, kH + kE};
      ga.seg[2] = {wembb + (size_t)t * kE, kT * kE, kH + kE, 2048};
      ga.seg[3] = {h1b, kH, 2048, 3072};
      ga.nseg = 4; ga.WT = WTg1; ga.ldk = 3072; ga.bias = bias_g1;
      ga.C = g1out; ga.C16 = nullptr; ga.ldc = 5120; ga.N = 5120; ga.Ktot = 3072; ga.act = 0;
      gemm_bf16<<<dim3(5120 / 64, kB / 64), 256, 0, stream>>>(ga);
    }
    step1_fused<<<kB, 256, 0, stream>>>(g1out, c1, h1b, img_proj, Vfeat,
                                        Wg, Ws_, bs_, wh, chat, chatb,
                                        out_alphas, out_betas, t);
    {  // g2: [128 x 4096], K = 3072
      GemmBArgs ga = {};
      ga.seg[0] = {chatb, kH, 0, kH};
      ga.seg[1] = {h1b, kH, kH, 2048};
      ga.seg[2] = {h2b, kH, 2048, 3072};
      ga.nseg = 3; ga.WT = WTg2; ga.ldk = 3072; ga.bias = bias_g2;
      ga.C = g1out; ga.C16 = nullptr; ga.ldc = 4096; ga.N = 4096; ga.Ktot = 3072; ga.act = 0;
      gemm_bf16<<<dim3(4096 / 64, kB / 64), 256, 0, stream>>>(ga);
    }
    lstm2_elem<<<(kB * kH + 255) / 256, 256, 0, stream>>>(
        g1out, c2, h2b, chat, sbufall + (size_t)t * kB * kH);
  }

  // ---- batched fc over all steps: [2560 x 12000], K = 1024
  {
    GemmBArgs ga = {};
    ga.seg[0] = {sbufall, kH, 0, kH};
    ga.nseg = 1; ga.WT = WTfc; ga.ldk = kH; ga.bias = b_fc;
    ga.C = out; ga.C16 = nullptr; ga.ldc = kT * kV; ga.N = kV; ga.Ktot = kH;
    ga.act = 0; ga.cmap = 1;
    gemm_bf16<<<dim3(12032 / 64, kT * kB / 64), 256, 0, stream>>>(ga);
  }
}

// Round 7
// 1828.981 us; speedup vs baseline: 1.2202x; 1.0481x over previous
//
#include <hip/hip_runtime.h>
#include <hip/hip_bf16.h>
#include <math.h>

typedef __attribute__((ext_vector_type(4))) float f32x4;
typedef __attribute__((ext_vector_type(8))) short bf16x8;

constexpr int kB = 128, kT = 20, kH = 1024, kE = 512, kP = 36, kRaw = 2048, kV = 12000;

__device__ __forceinline__ float sigf(float x) { return 1.0f / (1.0f + expf(-x)); }

#define AS1C const __attribute__((address_space(1))) void*
#define AS3P __attribute__((address_space(3))) void*

// ---------------------------------------------------------------- merged prep
// One kernel covering: zero c1/c2, zero h1b/h2b, images f32->bf16, WTv zero,
// WTfc pad zero, bias packing, embedding gather.
constexpr int NZ1 = 2 * kB * kH / 4;        // float4 zeros over c1,c2
constexpr int NZ2 = 2 * kB * kH * 2 / 16;   // uint4 zeros over h1b,h2b
constexpr int NCV = kB * kP * kRaw / 4;     // images -> bf16 (4 per thread)
constexpr int NPV = 64 * 1024 * 2 / 16;     // WTv zero (uint4)
constexpr int NPF = 32 * 1024 * 2 / 16;     // WTfc pad zero (uint4)
constexpr int NPB = 5120;                   // pack biases
constexpr int NGE = kB * kT * kE;           // gather embeddings

__global__ __launch_bounds__(256) void prep_small(
    float* c1z, uint4* h1z, const float* images, __hip_bfloat16* imagesb,
    uint4* wtv, uint4* wtfc_pad,
    const float* b_ih1, const float* b_hh1, const float* bx, const float* bh,
    const float* b_ih2, const float* b_hh2, float* bias_g1, float* bias_g2,
    const int* caps, const float* emb, __hip_bfloat16* wembb) {
  long idx = (long)blockIdx.x * 256 + threadIdx.x;
  if (idx < NZ1) { reinterpret_cast<float4*>(c1z)[idx] = make_float4(0, 0, 0, 0); return; }
  idx -= NZ1;
  if (idx < NZ2) { h1z[idx] = make_uint4(0, 0, 0, 0); return; }
  idx -= NZ2;
  if (idx < NCV) {
    float4 v = reinterpret_cast<const float4*>(images)[idx];
    __hip_bfloat16* d = imagesb + idx * 4;
    d[0] = __float2bfloat16(v.x); d[1] = __float2bfloat16(v.y);
    d[2] = __float2bfloat16(v.z); d[3] = __float2bfloat16(v.w);
    return;
  }
  idx -= NCV;
  if (idx < NPV) { wtv[idx] = make_uint4(0, 0, 0, 0); return; }
  idx -= NPV;
  if (idx < NPF) { wtfc_pad[idx] = make_uint4(0, 0, 0, 0); return; }
  idx -= NPF;
  if (idx < NPB) {
    int i = (int)idx;
    if (i < 4096) {
      bias_g1[i] = b_ih1[i] + b_hh1[i];
      bias_g2[i] = b_ih2[i] + b_hh2[i];
    } else {
      bias_g1[i] = bx[i - 4096] + bh[i - 4096];
    }
    return;
  }
  idx -= NPB;
  if (idx < NGE) {
    int e = (int)(idx % kE);
    int bt = (int)(idx / kE);
    int t = bt % kT;
    int b = bt / kT;
    int tok = caps[b * (kT + 1) + t];
    wembb[idx] = __float2bfloat16(emb[(size_t)tok * kE + e]);
  }
}

// ------------------------------------------------ merged weight transposes
struct TJob {
  const float* src; __hip_bfloat16* dst;
  int ld_src, K, N, lddst, koff, noff, blk_off, nbx;
};
struct TAll { TJob job[11]; int njobs; int total_blocks; };

__global__ __launch_bounds__(256) void transpose_all(TAll ta) {
  __shared__ float t[32][33];
  int bid = blockIdx.x;
  int ji = 0;
  while (ji + 1 < ta.njobs && bid >= ta.job[ji + 1].blk_off) ++ji;
  const TJob& J = ta.job[ji];
  int lbid = bid - J.blk_off;
  int n0 = (lbid % J.nbx) * 32, k0 = (lbid / J.nbx) * 32;
  int tx = threadIdx.x & 31, ty = threadIdx.x >> 5;  // 32 x 8
  #pragma unroll
  for (int i = 0; i < 32; i += 8) {
    int k = k0 + ty + i, n = n0 + tx;
    t[ty + i][tx] = (k < J.K && n < J.N) ? J.src[(size_t)k * J.ld_src + n] : 0.0f;
  }
  __syncthreads();
  #pragma unroll
  for (int i = 0; i < 32; i += 8) {
    int n = n0 + ty + i, k = k0 + tx;
    if (n < J.N && k < J.K)
      J.dst[(size_t)(n + J.noff) * J.lddst + k + J.koff] = __float2bfloat16(t[tx][ty + i]);
  }
}

// ------------------------------------------------------- 64x64 bf16 MFMA GEMM
// BK=128, 3-buffer counted-vmcnt pipeline. Used for g1/g2/glob/img_proj.
struct SegB { const __hip_bfloat16* A; int lda; int kstart; int kend; };
struct GemmBArgs {
  SegB seg[4]; int nseg;
  const __hip_bfloat16* WT; int ldk;
  const float* bias;
  float* C; __hip_bfloat16* C16; int ldc; int N; int Ktot; int act;
};

__global__ __launch_bounds__(256) void gemm_bf16(GemmBArgs ga) {
  __shared__ char lds[98304];  // 3 bufs x (A 16K | B 16K)
  const int bm = blockIdx.y * 64;
  const int bn = blockIdx.x * 64;
  const int tid = threadIdx.x;
  const int lane = tid & 63;
  const int w = tid >> 6;
  const int wr = w >> 1, wc = w & 1;

  int rowS[4], scbS[4], dstS[4];
  #pragma unroll
  for (int j = 0; j < 4; ++j) {
    int off = ((j * 4 + w) * 64 + lane) * 16;   // linear byte in 16 KB tile
    int row = off >> 8, colb = off & 255;       // 256 B rows (BK=128)
    rowS[j] = row;
    scbS[j] = colb ^ ((row & 7) << 4);
    dstS[j] = (j * 4 + w) * 1024;
  }

  f32x4 acc[2][2] = {};
  const int nit = ga.Ktot >> 7;

  auto stage = [&](int it, int buf) {
    const int k0 = it << 7;
    int si = 0;
    while (k0 >= ga.seg[si].kend) ++si;
    const __hip_bfloat16* Aseg = ga.seg[si].A;
    const int lda = ga.seg[si].lda;
    const int ks = k0 - ga.seg[si].kstart;
    char* baseA = lds + buf * 32768;
    char* baseB = baseA + 16384;
    #pragma unroll
    for (int j = 0; j < 4; ++j) {
      const __hip_bfloat16* sA = Aseg + (size_t)(bm + rowS[j]) * lda + ks + (scbS[j] >> 1);
      __builtin_amdgcn_global_load_lds((AS1C)sA, (AS3P)(baseA + dstS[j]), 16, 0, 0);
      const __hip_bfloat16* sB = ga.WT + (size_t)(bn + rowS[j]) * ga.ldk + k0 + (scbS[j] >> 1);
      __builtin_amdgcn_global_load_lds((AS1C)sB, (AS3P)(baseB + dstS[j]), 16, 0, 0);
    }
  };

  auto compute = [&](int buf) {
    const char* baseA = lds + buf * 32768;
    const char* baseB = baseA + 16384;
    #pragma unroll
    for (int kk = 0; kk < 4; ++kk) {
      bf16x8 a[2], b[2];
      #pragma unroll
      for (int f = 0; f < 2; ++f) {
        int row = wr * 32 + f * 16 + (lane & 15);
        int cb = kk * 64 + (lane >> 4) * 16;
        a[f] = *(const bf16x8*)(baseA + row * 256 + (cb ^ ((row & 7) << 4)));
        int nl = wc * 32 + f * 16 + (lane & 15);
        b[f] = *(const bf16x8*)(baseB + nl * 256 + (cb ^ ((nl & 7) << 4)));
      }
      #pragma unroll
      for (int fm = 0; fm < 2; ++fm)
        #pragma unroll
        for (int fn = 0; fn < 2; ++fn)
          acc[fm][fn] = __builtin_amdgcn_mfma_f32_16x16x32_bf16(a[fm], b[fn], acc[fm][fn], 0, 0, 0);
    }
  };

  stage(0, 0);
  stage(1, 1);
  asm volatile("s_waitcnt vmcnt(8)" ::: "memory");
  __builtin_amdgcn_s_barrier();
  int cbuf = 0;
  for (int it = 0; it < nit; ++it) {
    if (it + 2 < nit) {
      int sb = cbuf + 2; if (sb >= 3) sb -= 3;
      stage(it + 2, sb);
    }
    compute(cbuf);
    if (it + 1 < nit) {
      if (it + 2 < nit) asm volatile("s_waitcnt vmcnt(8)" ::: "memory");
      else              asm volatile("s_waitcnt vmcnt(0)" ::: "memory");
      __builtin_amdgcn_s_barrier();
    }
    ++cbuf; if (cbuf == 3) cbuf = 0;
  }

  #pragma unroll
  for (int fm = 0; fm < 2; ++fm) {
    int rbase = bm + wr * 32 + fm * 16 + (lane >> 4) * 4;
    #pragma unroll
    for (int fn = 0; fn < 2; ++fn) {
      int col = bn + wc * 32 + fn * 16 + (lane & 15);
      if (col >= ga.N) continue;
      float bv = ga.bias ? ga.bias[col] : 0.0f;
      #pragma unroll
      for (int j = 0; j < 4; ++j) {
        float v = acc[fm][fn][j] + bv;
        if (ga.act == 1) v = fmaxf(v, 0.0f);
        size_t off = (size_t)(rbase + j) * ga.ldc + col;
        if (ga.C) ga.C[off] = v;
        if (ga.C16) ga.C16[off] = __float2bfloat16(v);
      }
    }
  }
}

// ------------------------------------------- 128x128 m97-structure bf16 GEMM
// BK=64, 4 waves x (64x64), acc 4x4, 3-buffer counted vmcnt(8), XCD swizzle.
// Single A segment. cmap==1: row m -> C[(m&127)*ldc + (m>>7)*kV + col].
struct G128Args {
  const __hip_bfloat16* A; int lda;
  const __hip_bfloat16* WT; int ldk;
  const float* bias;
  float* C; __hip_bfloat16* C16; int ldc; int N; int Ktot; int act; int cmap;
};

__global__ __launch_bounds__(256) void gemm128(G128Args ga) {
  __shared__ char lds[98304];  // 3 bufs x (A 16K | B 16K)
  // bijective XCD swizzle (m204)
  const int gx = gridDim.x;
  const int nwg = gx * gridDim.y;
  int bid = blockIdx.y * gx + blockIdx.x;
  int q = nwg >> 3, r = nwg & 7;
  int xc = bid & 7, yq = bid >> 3;
  int swz = (xc < r ? xc * (q + 1) : r * (q + 1) + (xc - r) * q) + yq;
  const int bn = (swz % gx) * 128;
  const int bm = (swz / gx) * 128;

  const int tid = threadIdx.x;
  const int lane = tid & 63;
  const int w = tid >> 6;
  const int wr = w >> 1, wc = w & 1;

  int rowS[4], scbS[4], dstS[4];
  #pragma unroll
  for (int j = 0; j < 4; ++j) {
    int off = ((j * 4 + w) * 64 + lane) * 16;   // linear byte in 16 KB tile
    int row = off >> 7, colb = off & 127;       // 128 B rows (BK=64)
    rowS[j] = row;
    scbS[j] = colb ^ ((row & 7) << 4);
    dstS[j] = (j * 4 + w) * 1024;
  }

  f32x4 acc[4][4] = {};
  const int nit = ga.Ktot >> 6;

  auto stage = [&](int it, int buf) {
    const int k0 = it << 6;
    char* baseA = lds + buf * 32768;
    char* baseB = baseA + 16384;
    #pragma unroll
    for (int j = 0; j < 4; ++j) {
      const __hip_bfloat16* sA = ga.A + (size_t)(bm + rowS[j]) * ga.lda + k0 + (scbS[j] >> 1);
      __builtin_amdgcn_global_load_lds((AS1C)sA, (AS3P)(baseA + dstS[j]), 16, 0, 0);
      const __hip_bfloat16* sB = ga.WT + (size_t)(bn + rowS[j]) * ga.ldk + k0 + (scbS[j] >> 1);
      __builtin_amdgcn_global_load_lds((AS1C)sB, (AS3P)(baseB + dstS[j]), 16, 0, 0);
    }
  };

  auto compute = [&](int buf) {
    const char* baseA = lds + buf * 32768;
    const char* baseB = baseA + 16384;
    #pragma unroll
    for (int kk = 0; kk < 2; ++kk) {
      bf16x8 a[4], b[4];
      int cb = kk * 64 + (lane >> 4) * 16;
      #pragma unroll
      for (int f = 0; f < 4; ++f) {
        int row = wr * 64 + f * 16 + (lane & 15);
        a[f] = *(const bf16x8*)(baseA + row * 128 + (cb ^ ((row & 7) << 4)));
        int nl = wc * 64 + f * 16 + (lane & 15);
        b[f] = *(const bf16x8*)(baseB + nl * 128 + (cb ^ ((nl & 7) << 4)));
      }
      #pragma unroll
      for (int fm = 0; fm < 4; ++fm)
        #pragma unroll
        for (int fn = 0; fn < 4; ++fn)
          acc[fm][fn] = __builtin_amdgcn_mfma_f32_16x16x32_bf16(a[fm], b[fn], acc[fm][fn], 0, 0, 0);
    }
  };

  stage(0, 0);
  stage(1, 1);
  asm volatile("s_waitcnt vmcnt(8)" ::: "memory");
  __builtin_amdgcn_s_barrier();
  int cbuf = 0;
  for (int it = 0; it < nit; ++it) {
    if (it + 2 < nit) {
      int sb = cbuf + 2; if (sb >= 3) sb -= 3;
      stage(it + 2, sb);
    }
    compute(cbuf);
    if (it + 1 < nit) {
      if (it + 2 < nit) asm volatile("s_waitcnt vmcnt(8)" ::: "memory");
      else              asm volatile("s_waitcnt vmcnt(0)" ::: "memory");
      __builtin_amdgcn_s_barrier();
    }
    ++cbuf; if (cbuf == 3) cbuf = 0;
  }

  #pragma unroll
  for (int fm = 0; fm < 4; ++fm) {
    int rbase = bm + wr * 64 + fm * 16 + (lane >> 4) * 4;
    #pragma unroll
    for (int fn = 0; fn < 4; ++fn) {
      int col = bn + wc * 64 + fn * 16 + (lane & 15);
      if (col >= ga.N) continue;
      float bv = ga.bias ? ga.bias[col] : 0.0f;
      #pragma unroll
      for (int j = 0; j < 4; ++j) {
        float v = acc[fm][fn][j] + bv;
        if (ga.act == 1) v = fmaxf(v, 0.0f);
        int m = rbase + j;
        size_t off = ga.cmap == 1
            ? (size_t)(m & 127) * ga.ldc + (size_t)(m >> 7) * kV + col
            : (size_t)m * ga.ldc + col;
        if (ga.C) ga.C[off] = v;
        if (ga.C16) ga.C16[off] = __float2bfloat16(v);
      }
    }
  }
}

// ------------------------------------------------------- small fused kernels
__global__ __launch_bounds__(256) void mean_p(const float* __restrict__ Vfeat,
                                              __hip_bfloat16* __restrict__ meanVb) {
  int idx = blockIdx.x * 256 + threadIdx.x;
  if (idx >= kB * kH) return;
  int b = idx >> 10, h = idx & 1023;
  float sm = 0.0f;
  for (int p = 0; p < kP; ++p) sm += Vfeat[((size_t)b * kP + p) * kH + h];
  meanVb[idx] = __float2bfloat16(sm * (1.0f / kP));
}

// LSTM1 gates + sentinel + full adaptive-attention step. One block per batch.
__global__ __launch_bounds__(256) void step1_fused(
    const float* __restrict__ g, float* __restrict__ c1,
    __hip_bfloat16* __restrict__ h1b,
    const float* __restrict__ img_proj, const float* __restrict__ Vfeat,
    const float* __restrict__ Wg, const float* __restrict__ Ws,
    const float* __restrict__ bs, const float* __restrict__ wh,
    float* __restrict__ c_hat, __hip_bfloat16* __restrict__ c_hatb,
    float* __restrict__ out_alphas, float* __restrict__ out_betas, int t) {
  const int b = blockIdx.x;
  const int tid = threadIdx.x;
  const int lane = tid & 63;
  const int w = tid >> 6;
  __shared__ float sh_h1[kH];
  __shared__ float sh_st[kH];
  __shared__ float wsum[4][36];
  __shared__ float htp[36];
  __shared__ float stp[36];
  __shared__ float alpha[kP];
  __shared__ float sred[4];  // 0: att_vs, 1: beta, 2: zmax, 3: zsum

  const float* gr = g + (size_t)b * 5120;
  #pragma unroll
  for (int i = 0; i < 4; ++i) {
    int h = tid + i * 256;
    float ig = sigf(gr[h]);
    float fg = sigf(gr[kH + h]);
    float gg = tanhf(gr[2 * kH + h]);
    float og = sigf(gr[3 * kH + h]);
    int idx = b * kH + h;
    float c = fg * c1[idx] + ig * gg;
    float tc = tanhf(c);
    float hn = og * tc;
    c1[idx] = c;
    h1b[idx] = __float2bfloat16(hn);
    sh_h1[h] = hn;
    sh_st[h] = sigf(gr[4 * kH + h]) * tc;
  }
  __syncthreads();

  #pragma unroll
  for (int pass = 0; pass < 2; ++pass) {
    const float* vec = pass == 0 ? sh_h1 : sh_st;
    const float* W = pass == 0 ? Wg : Ws;
    float pg[36];
    #pragma unroll
    for (int j = 0; j < 36; ++j) pg[j] = 0.0f;
    #pragma unroll
    for (int i = 0; i < 4; ++i) {
      int hh = tid + i * 256;
      float hv = vec[hh];
      const float4* wrow = reinterpret_cast<const float4*>(W + (size_t)hh * 36);
      #pragma unroll
      for (int r = 0; r < 9; ++r) {
        float4 wv = wrow[r];
        pg[4 * r + 0] = fmaf(hv, wv.x, pg[4 * r + 0]);
        pg[4 * r + 1] = fmaf(hv, wv.y, pg[4 * r + 1]);
        pg[4 * r + 2] = fmaf(hv, wv.z, pg[4 * r + 2]);
        pg[4 * r + 3] = fmaf(hv, wv.w, pg[4 * r + 3]);
      }
    }
    #pragma unroll
    for (int j = 0; j < 36; ++j) {
      float v = pg[j];
      #pragma unroll
      for (int off = 32; off > 0; off >>= 1) v += __shfl_down(v, off, 64);
      if (lane == 0) wsum[w][j] = v;
    }
    __syncthreads();
    if (tid < 36) {
      float s = wsum[0][tid] + wsum[1][tid] + wsum[2][tid] + wsum[3][tid];
      if (pass == 0) htp[tid] = s; else stp[tid] = s;
    }
    __syncthreads();
  }

  if (w == 0) {
    float zz_r = -3.0e38f;
    if (lane < kP) {
      const float* ip = img_proj + ((size_t)b * kP + lane) * kP;
      float acc = 0.0f;
      #pragma unroll
      for (int j = 0; j < kP; ++j) acc = fmaf(tanhf(ip[j] + htp[j]), wh[j], acc);
      zz_r = acc;
    }
    float m = zz_r;
    #pragma unroll
    for (int off = 32; off > 0; off >>= 1) m = fmaxf(m, __shfl_xor(m, off, 64));
    float e = (lane < kP) ? expf(zz_r - m) : 0.0f;
    float s = e;
    #pragma unroll
    for (int off = 32; off > 0; off >>= 1) s += __shfl_xor(s, off, 64);
    if (lane < kP) alpha[lane] = e / s;
    if (lane == 0) { sred[2] = m; sred[3] = s; }
  } else if (w == 1) {
    float tv = 0.0f;
    if (lane < kP) tv = tanhf(stp[lane] + bs[lane] + htp[lane]) * wh[lane];
    #pragma unroll
    for (int off = 32; off > 0; off >>= 1) tv += __shfl_xor(tv, off, 64);
    if (lane == 0) sred[0] = tv;
  }
  __syncthreads();
  if (tid == 0) {
    float av = sred[0], m = sred[2], s = sred[3];
    float m2 = fmaxf(m, av);
    float eb = expf(av - m2);
    float beta = eb / (s * expf(m - m2) + eb);
    sred[1] = beta;
    out_betas[b * kT + t] = beta;
  }
  __syncthreads();
  if (tid < kP) out_alphas[((size_t)b * kT + t) * kP + tid] = alpha[tid];
  const float beta = sred[1];
  #pragma unroll
  for (int i = 0; i < 4; ++i) {
    int h = tid + i * 256;
    float ctx = 0.0f;
    for (int p = 0; p < kP; ++p) ctx = fmaf(alpha[p], Vfeat[((size_t)b * kP + p) * kH + h], ctx);
    float v = beta * sh_st[h] + (1.0f - beta) * ctx;
    c_hat[(size_t)b * kH + h] = v;
    c_hatb[(size_t)b * kH + h] = __float2bfloat16(v);
  }
}

// g layout: [b][4096]; sbufb points at this step's [B][H] slice.
__global__ __launch_bounds__(256) void lstm2_elem(const float* __restrict__ g,
                                                  float* __restrict__ c2,
                                                  __hip_bfloat16* __restrict__ h2b,
                                                  const float* __restrict__ c_hat,
                                                  __hip_bfloat16* __restrict__ sbufb) {
  int idx = blockIdx.x * 256 + threadIdx.x;
  if (idx >= kB * kH) return;
  int b = idx >> 10, h = idx & 1023;
  const float* gr = g + (size_t)b * 4 * kH;
  float ig = sigf(gr[h]);
  float fg = sigf(gr[kH + h]);
  float gg = tanhf(gr[2 * kH + h]);
  float og = sigf(gr[3 * kH + h]);
  float c = fg * c2[idx] + ig * gg;
  float hn = og * tanhf(c);
  c2[idx] = c;
  h2b[idx] = __float2bfloat16(hn);
  sbufb[idx] = __float2bfloat16(c_hat[idx] + hn);
}

// ------------------------------------------------------------------ launch
extern "C" void kernel_launch(void* const* d_in, const int* in_sizes, int n_in,
                              void* d_out, int out_size, void* d_ws, size_t ws_size,
                              hipStream_t stream) {
  const float* images  = (const float*)d_in[0];
  const int*   caps    = (const int*)d_in[1];
  const float* W_img   = (const float*)d_in[3];
  const float* b_img   = (const float*)d_in[4];
  const float* W_glob  = (const float*)d_in[5];
  const float* b_glob  = (const float*)d_in[6];
  const float* W_ih1   = (const float*)d_in[7];
  const float* W_hh1   = (const float*)d_in[8];
  const float* b_ih1   = (const float*)d_in[9];
  const float* b_hh1   = (const float*)d_in[10];
  const float* Wx_gate = (const float*)d_in[11];
  const float* bx_gate = (const float*)d_in[12];
  const float* Wh_gate = (const float*)d_in[13];
  const float* bh_gate = (const float*)d_in[14];
  const float* W_ih2   = (const float*)d_in[15];
  const float* W_hh2   = (const float*)d_in[16];
  const float* b_ih2   = (const float*)d_in[17];
  const float* b_hh2   = (const float*)d_in[18];
  const float* Wv      = (const float*)d_in[19];
  const float* bv      = (const float*)d_in[20];
  const float* Ws_     = (const float*)d_in[21];
  const float* bs_     = (const float*)d_in[22];
  const float* Wg      = (const float*)d_in[23];
  const float* wh      = (const float*)d_in[24];
  const float* emb     = (const float*)d_in[25];
  const float* W_fc    = (const float*)d_in[26];
  const float* b_fc    = (const float*)d_in[27];

  float* out = (float*)d_out;
  float* out_alphas = out + (size_t)kB * kT * kV;
  float* out_betas  = out_alphas + (size_t)kB * kT * kP;

  char* base = (char*)d_ws;
  auto alloc = [&](size_t bytes) {
    char* p = base;
    base += (bytes + 255) & ~(size_t)255;
    return p;
  };
  float*          Vfeat   = (float*)alloc((size_t)kB * kP * kH * 4);
  __hip_bfloat16* Vfeatb  = (__hip_bfloat16*)alloc((size_t)kB * kP * kH * 2);
  __hip_bfloat16* imagesb = (__hip_bfloat16*)alloc((size_t)kB * kP * kRaw * 2);
  __hip_bfloat16* WTg1    = (__hip_bfloat16*)alloc((size_t)5120 * 3072 * 2);
  __hip_bfloat16* WTg2    = (__hip_bfloat16*)alloc((size_t)4096 * 3072 * 2);
  __hip_bfloat16* WTfc    = (__hip_bfloat16*)alloc((size_t)12032 * 1024 * 2);
  __hip_bfloat16* WTimg   = (__hip_bfloat16*)alloc((size_t)1024 * 2048 * 2);
  __hip_bfloat16* WTglob  = (__hip_bfloat16*)alloc((size_t)512 * 1024 * 2);
  __hip_bfloat16* WTv     = (__hip_bfloat16*)alloc((size_t)64 * 1024 * 2);
  __hip_bfloat16* wembb   = (__hip_bfloat16*)alloc((size_t)kB * kT * kE * 2);
  float*          img_proj= (float*)alloc((size_t)kB * kP * kP * 4);
  __hip_bfloat16* globb   = (__hip_bfloat16*)alloc((size_t)kB * kE * 2);
  __hip_bfloat16* meanVb  = (__hip_bfloat16*)alloc((size_t)kB * kH * 2);
  float*          c1      = (float*)alloc((size_t)2 * kB * kH * 4);  // c1, c2
  float*          c2      = c1 + kB * kH;
  __hip_bfloat16* h1b     = (__hip_bfloat16*)alloc((size_t)2 * kB * kH * 2);
  __hip_bfloat16* h2b     = h1b + kB * kH;
  float*          g1out   = (float*)alloc((size_t)kB * 5120 * 4);
  float*          chat    = (float*)alloc((size_t)kB * kH * 4);
  __hip_bfloat16* chatb   = (__hip_bfloat16*)alloc((size_t)kB * kH * 2);
  __hip_bfloat16* sbufall = (__hip_bfloat16*)alloc((size_t)kT * kB * kH * 2);  // [t][b][h]
  float*          bias_g1 = (float*)alloc(5120 * 4);
  float*          bias_g2 = (float*)alloc(4096 * 4);

  // ---- merged prep (1 launch)
  {
    long total = (long)NZ1 + NZ2 + NCV + NPV + NPF + NPB + NGE;
    int blocks = (int)((total + 255) / 256);
    prep_small<<<blocks, 256, 0, stream>>>(
        c1, (uint4*)h1b, images, imagesb, (uint4*)WTv,
        (uint4*)(WTfc + (size_t)12000 * 1024),
        b_ih1, b_hh1, bx_gate, bh_gate, b_ih2, b_hh2, bias_g1, bias_g2,
        caps, emb, wembb);
  }
  // ---- merged transposes (1 launch)
  {
    TAll ta = {};
    int off = 0, j = 0;
    auto add = [&](const float* src, int ldsrc, int K, int N, __hip_bfloat16* dst,
                   int lddst, int koff, int noff) {
      int nbx = (N + 31) / 32, nby = (K + 31) / 32;
      ta.job[j] = {src, dst, ldsrc, K, N, lddst, koff, noff, off, nbx};
      off += nbx * nby;
      ++j;
    };
    add(W_img,   kH,     kRaw, kH,     WTimg,  kRaw, 0, 0);
    add(W_glob,  kE,     kH,   kE,     WTglob, kH,   0, 0);
    add(Wv,      kP,     kH,   kP,     WTv,    kH,   0, 0);
    add(W_ih1,   4 * kH, 2048, 4 * kH, WTg1,   3072, 0, 0);
    add(W_hh1,   4 * kH, 1024, 4 * kH, WTg1,   3072, 2048, 0);
    add(Wx_gate, kH,     2048, kH,     WTg1,   3072, 0, 4096);
    add(Wh_gate, kH,     1024, kH,     WTg1,   3072, 2048, 4096);
    add(W_ih2,   4 * kH, 2048, 4 * kH, WTg2,   3072, 0, 0);
    add(W_hh2,   4 * kH, 1024, 4 * kH, WTg2,   3072, 2048, 0);
    add(W_fc,    kV,     kH,   kV,     WTfc,   kH,   0, 0);
    ta.njobs = j;
    ta.total_blocks = off;
    transpose_all<<<off, 256, 0, stream>>>(ta);
  }

  // Vfeat = relu(images @ W_img + b_img)   [4608 x 1024], K=2048  (128^2 tile)
  {
    G128Args ga = {};
    ga.A = imagesb; ga.lda = kRaw; ga.WT = WTimg; ga.ldk = kRaw; ga.bias = b_img;
    ga.C = Vfeat; ga.C16 = Vfeatb; ga.ldc = kH; ga.N = kH; ga.Ktot = kRaw;
    ga.act = 1; ga.cmap = 0;
    gemm128<<<dim3(kH / 128, kB * kP / 128), 256, 0, stream>>>(ga);
  }
  mean_p<<<(kB * kH + 255) / 256, 256, 0, stream>>>(Vfeat, meanVb);
  // glob = relu(meanV @ W_glob + b_glob)
  {
    GemmBArgs ga = {};
    ga.seg[0] = {meanVb, kH, 0, kH};
    ga.nseg = 1; ga.WT = WTglob; ga.ldk = kH; ga.bias = b_glob;
    ga.C = nullptr; ga.C16 = globb; ga.ldc = kE; ga.N = kE; ga.Ktot = kH; ga.act = 1;
    gemm_bf16<<<dim3(kE / 64, kB / 64), 256, 0, stream>>>(ga);
  }
  // img_proj = Vfeat @ Wv + bv
  {
    GemmBArgs ga = {};
    ga.seg[0] = {Vfeatb, kH, 0, kH};
    ga.nseg = 1; ga.WT = WTv; ga.ldk = kH; ga.bias = bv;
    ga.C = img_proj; ga.C16 = nullptr; ga.ldc = kP; ga.N = kP; ga.Ktot = kH; ga.act = 0;
    gemm_bf16<<<dim3(1, kB * kP / 64), 256, 0, stream>>>(ga);
  }

  // ---- 20 decode steps (4 kernels each; fc deferred)
  for (int t = 0; t < kT; ++t) {
    {  // g1 + sentinel: [128 x 5120], K = 3072
      GemmBArgs ga = {};
      ga.seg[0] = {h2b, kH, 0, kH};
      ga.seg[1] = {globb, kE, kH, kH + kE};
      ga.seg[2] = {wembb + (size_t)t * kE, kT * kE, kH + kE, 2048};
      ga.seg[3] = {h1b, kH, 2048, 3072};
      ga.nseg = 4; ga.WT = WTg1; ga.ldk = 3072; ga.bias = bias_g1;
      ga.C = g1out; ga.C16 = nullptr; ga.ldc = 5120; ga.N = 5120; ga.Ktot = 3072; ga.act = 0;
      gemm_bf16<<<dim3(5120 / 64, kB / 64), 256, 0, stream>>>(ga);
    }
    step1_fused<<<kB, 256, 0, stream>>>(g1out, c1, h1b, img_proj, Vfeat,
                                        Wg, Ws_, bs_, wh, chat, chatb,
                                        out_alphas, out_betas, t);
    {  // g2: [128 x 4096], K = 3072
      GemmBArgs ga = {};
      ga.seg[0] = {chatb, kH, 0, kH};
      ga.seg[1] = {h1b, kH, kH, 2048};
      ga.seg[2] = {h2b, kH, 2048, 3072};
      ga.nseg = 3; ga.WT = WTg2; ga.ldk = 3072; ga.bias = bias_g2;
      ga.C = g1out; ga.C16 = nullptr; ga.ldc = 4096; ga.N = 4096; ga.Ktot = 3072; ga.act = 0;
      gemm_bf16<<<dim3(4096 / 64, kB / 64), 256, 0, stream>>>(ga);
    }
    lstm2_elem<<<(kB * kH + 255) / 256, 256, 0, stream>>>(
        g1out, c2, h2b, chat, sbufall + (size_t)t * kB * kH);
  }

  // ---- batched fc over all steps: [2560 x 12000], K = 1024  (128^2 tile)
  {
    G128Args ga = {};
    ga.A = sbufall; ga.lda = kH; ga.WT = WTfc; ga.ldk = kH; ga.bias = b_fc;
    ga.C = out; ga.C16 = nullptr; ga.ldc = kT * kV; ga.N = kV; ga.Ktot = kH;
    ga.act = 0; ga.cmap = 1;
    gemm128<<<dim3(12032 / 128, kT * kB / 128), 256, 0, stream>>>(ga);
  }
}

// Round 8
// 1587.785 us; speedup vs baseline: 1.4056x; 1.1519x over previous
//
#include <hip/hip_runtime.h>
#include <hip/hip_bf16.h>
#include <math.h>

typedef __attribute__((ext_vector_type(4))) float f32x4;
typedef __attribute__((ext_vector_type(8))) short bf16x8;

constexpr int kB = 128, kT = 20, kH = 1024, kE = 512, kP = 36, kRaw = 2048, kV = 12000;

__device__ __forceinline__ float sigf(float x) { return 1.0f / (1.0f + expf(-x)); }

#define AS1C const __attribute__((address_space(1))) void*
#define AS3P __attribute__((address_space(3))) void*

// ---------------------------------------------------------------- merged prep
constexpr int NZ1 = 2 * kB * kH / 4;        // float4 zeros over c1,c2
constexpr int NZ2 = 2 * kB * kH * 2 / 16;   // uint4 zeros over h1b,h2b
constexpr int NCV = kB * kP * kRaw / 4;     // images -> bf16 (4 per thread)
constexpr int NPV = 64 * 1024 * 2 / 16;     // WTv zero (uint4)
constexpr int NPF = 32 * 1024 * 2 / 16;     // WTfc pad zero (uint4)
constexpr int NPB = 5120;                   // pack biases
constexpr int NGE = kB * kT * kE;           // gather embeddings

__global__ __launch_bounds__(256) void prep_small(
    float* c1z, uint4* h1z, const float* images, __hip_bfloat16* imagesb,
    uint4* wtv, uint4* wtfc_pad,
    const float* b_ih1, const float* b_hh1, const float* bx, const float* bh,
    const float* b_ih2, const float* b_hh2, float* bias_g1, float* bias_g2,
    const int* caps, const float* emb, __hip_bfloat16* wembb) {
  long idx = (long)blockIdx.x * 256 + threadIdx.x;
  if (idx < NZ1) { reinterpret_cast<float4*>(c1z)[idx] = make_float4(0, 0, 0, 0); return; }
  idx -= NZ1;
  if (idx < NZ2) { h1z[idx] = make_uint4(0, 0, 0, 0); return; }
  idx -= NZ2;
  if (idx < NCV) {
    float4 v = reinterpret_cast<const float4*>(images)[idx];
    __hip_bfloat16* d = imagesb + idx * 4;
    d[0] = __float2bfloat16(v.x); d[1] = __float2bfloat16(v.y);
    d[2] = __float2bfloat16(v.z); d[3] = __float2bfloat16(v.w);
    return;
  }
  idx -= NCV;
  if (idx < NPV) { wtv[idx] = make_uint4(0, 0, 0, 0); return; }
  idx -= NPV;
  if (idx < NPF) { wtfc_pad[idx] = make_uint4(0, 0, 0, 0); return; }
  idx -= NPF;
  if (idx < NPB) {
    int i = (int)idx;
    if (i < 4096) {
      bias_g1[i] = b_ih1[i] + b_hh1[i];
      bias_g2[i] = b_ih2[i] + b_hh2[i];
    } else {
      bias_g1[i] = bx[i - 4096] + bh[i - 4096];
    }
    return;
  }
  idx -= NPB;
  if (idx < NGE) {
    int e = (int)(idx % kE);
    int bt = (int)(idx / kE);
    int t = bt % kT;
    int b = bt / kT;
    int tok = caps[b * (kT + 1) + t];
    wembb[idx] = __float2bfloat16(emb[(size_t)tok * kE + e]);
  }
}

// ------------------------------------------------ merged weight transposes
struct TJob {
  const float* src; __hip_bfloat16* dst;
  int ld_src, K, N, lddst, koff, noff, blk_off, nbx;
};
struct TAll { TJob job[11]; int njobs; int total_blocks; };

__global__ __launch_bounds__(256) void transpose_all(TAll ta) {
  __shared__ float t[32][33];
  int bid = blockIdx.x;
  int ji = 0;
  while (ji + 1 < ta.njobs && bid >= ta.job[ji + 1].blk_off) ++ji;
  const TJob& J = ta.job[ji];
  int lbid = bid - J.blk_off;
  int n0 = (lbid % J.nbx) * 32, k0 = (lbid / J.nbx) * 32;
  int tx = threadIdx.x & 31, ty = threadIdx.x >> 5;  // 32 x 8
  #pragma unroll
  for (int i = 0; i < 32; i += 8) {
    int k = k0 + ty + i, n = n0 + tx;
    t[ty + i][tx] = (k < J.K && n < J.N) ? J.src[(size_t)k * J.ld_src + n] : 0.0f;
  }
  __syncthreads();
  #pragma unroll
  for (int i = 0; i < 32; i += 8) {
    int n = n0 + ty + i, k = k0 + tx;
    if (n < J.N && k < J.K)
      J.dst[(size_t)(n + J.noff) * J.lddst + k + J.koff] = __float2bfloat16(t[tx][ty + i]);
  }
}

// ------------------------------------------------------- 64x64 bf16 MFMA GEMM
// BK=128, 2-buffer counted-vmcnt pipeline (64 KB LDS -> 2 blocks/CU).
// Optional split-K via gridDim.z: z computes K-range slab into C + z*zstride.
struct SegB { const __hip_bfloat16* A; int lda; int kstart; int kend; };
struct GemmBArgs {
  SegB seg[4]; int nseg;
  const __hip_bfloat16* WT; int ldk;
  const float* bias;
  float* C; __hip_bfloat16* C16; int ldc; int N; int Ktot; int act; int zstride;
};

__global__ __launch_bounds__(256) void gemm_bf16(GemmBArgs ga) {
  __shared__ char lds[65536];  // 2 bufs x (A 16K | B 16K)
  const int bm = blockIdx.y * 64;
  const int bn = blockIdx.x * 64;
  const int tid = threadIdx.x;
  const int lane = tid & 63;
  const int w = tid >> 6;
  const int wr = w >> 1, wc = w & 1;

  int rowS[4], scbS[4], dstS[4];
  #pragma unroll
  for (int j = 0; j < 4; ++j) {
    int off = ((j * 4 + w) * 64 + lane) * 16;   // linear byte in 16 KB tile
    int row = off >> 8, colb = off & 255;       // 256 B rows (BK=128)
    rowS[j] = row;
    scbS[j] = colb ^ ((row & 7) << 4);
    dstS[j] = (j * 4 + w) * 1024;
  }

  f32x4 acc[2][2] = {};
  const int nz = gridDim.z;
  const int nit = (ga.Ktot >> 7) / nz;
  const int it0 = blockIdx.z * nit;
  float* C = ga.C + (size_t)blockIdx.z * ga.zstride;

  auto stage = [&](int it, int buf) {
    const int k0 = it << 7;
    int si = 0;
    while (k0 >= ga.seg[si].kend) ++si;
    const __hip_bfloat16* Aseg = ga.seg[si].A;
    const int lda = ga.seg[si].lda;
    const int ks = k0 - ga.seg[si].kstart;
    char* baseA = lds + buf * 32768;
    char* baseB = baseA + 16384;
    #pragma unroll
    for (int j = 0; j < 4; ++j) {
      const __hip_bfloat16* sA = Aseg + (size_t)(bm + rowS[j]) * lda + ks + (scbS[j] >> 1);
      __builtin_amdgcn_global_load_lds((AS1C)sA, (AS3P)(baseA + dstS[j]), 16, 0, 0);
      const __hip_bfloat16* sB = ga.WT + (size_t)(bn + rowS[j]) * ga.ldk + k0 + (scbS[j] >> 1);
      __builtin_amdgcn_global_load_lds((AS1C)sB, (AS3P)(baseB + dstS[j]), 16, 0, 0);
    }
  };

  auto compute = [&](int buf) {
    const char* baseA = lds + buf * 32768;
    const char* baseB = baseA + 16384;
    #pragma unroll
    for (int kk = 0; kk < 4; ++kk) {
      bf16x8 a[2], b[2];
      #pragma unroll
      for (int f = 0; f < 2; ++f) {
        int row = wr * 32 + f * 16 + (lane & 15);
        int cb = kk * 64 + (lane >> 4) * 16;
        a[f] = *(const bf16x8*)(baseA + row * 256 + (cb ^ ((row & 7) << 4)));
        int nl = wc * 32 + f * 16 + (lane & 15);
        b[f] = *(const bf16x8*)(baseB + nl * 256 + (cb ^ ((nl & 7) << 4)));
      }
      #pragma unroll
      for (int fm = 0; fm < 2; ++fm)
        #pragma unroll
        for (int fn = 0; fn < 2; ++fn)
          acc[fm][fn] = __builtin_amdgcn_mfma_f32_16x16x32_bf16(a[fm], b[fn], acc[fm][fn], 0, 0, 0);
    }
  };

  stage(it0, 0);
  stage(it0 + 1, 1);
  asm volatile("s_waitcnt vmcnt(8)" ::: "memory");
  __builtin_amdgcn_s_barrier();
  int cur = 0;
  for (int i = 0; i < nit; ++i) {
    compute(cur);
    __builtin_amdgcn_s_barrier();                 // all waves done reading buf cur
    if (i + 2 < nit) stage(it0 + i + 2, cur);     // overwrite buf cur
    if (i + 1 < nit) {
      if (i + 2 < nit) asm volatile("s_waitcnt vmcnt(8)" ::: "memory");
      else             asm volatile("s_waitcnt vmcnt(0)" ::: "memory");
      __builtin_amdgcn_s_barrier();               // buf cur^1 ready
    }
    cur ^= 1;
  }

  #pragma unroll
  for (int fm = 0; fm < 2; ++fm) {
    int rbase = bm + wr * 32 + fm * 16 + (lane >> 4) * 4;
    #pragma unroll
    for (int fn = 0; fn < 2; ++fn) {
      int col = bn + wc * 32 + fn * 16 + (lane & 15);
      if (col >= ga.N) continue;
      float bv = ga.bias ? ga.bias[col] : 0.0f;
      #pragma unroll
      for (int j = 0; j < 4; ++j) {
        float v = acc[fm][fn][j] + bv;
        if (ga.act == 1) v = fmaxf(v, 0.0f);
        size_t off = (size_t)(rbase + j) * ga.ldc + col;
        if (ga.C) C[off] = v;
        if (ga.C16) ga.C16[off] = __float2bfloat16(v);
      }
    }
  }
}

// ------------------------------------------- 128x128 m97-structure bf16 GEMM
// BK=64, 4 waves x (64x64), acc 4x4, 2-buffer counted vmcnt, XCD swizzle.
// cmap==1: row m -> C[(m&127)*ldc + (m>>7)*kV + col].
struct G128Args {
  const __hip_bfloat16* A; int lda;
  const __hip_bfloat16* WT; int ldk;
  const float* bias;
  float* C; __hip_bfloat16* C16; int ldc; int N; int Ktot; int act; int cmap;
};

__global__ __launch_bounds__(256) void gemm128(G128Args ga) {
  __shared__ char lds[65536];  // 2 bufs x (A 16K | B 16K)
  const int gx = gridDim.x;
  const int nwg = gx * gridDim.y;
  int bid = blockIdx.y * gx + blockIdx.x;
  int q = nwg >> 3, r = nwg & 7;
  int xc = bid & 7, yq = bid >> 3;
  int swz = (xc < r ? xc * (q + 1) : r * (q + 1) + (xc - r) * q) + yq;
  const int bn = (swz % gx) * 128;
  const int bm = (swz / gx) * 128;

  const int tid = threadIdx.x;
  const int lane = tid & 63;
  const int w = tid >> 6;
  const int wr = w >> 1, wc = w & 1;

  int rowS[4], scbS[4], dstS[4];
  #pragma unroll
  for (int j = 0; j < 4; ++j) {
    int off = ((j * 4 + w) * 64 + lane) * 16;   // linear byte in 16 KB tile
    int row = off >> 7, colb = off & 127;       // 128 B rows (BK=64)
    rowS[j] = row;
    scbS[j] = colb ^ ((row & 7) << 4);
    dstS[j] = (j * 4 + w) * 1024;
  }

  f32x4 acc[4][4] = {};
  const int nit = ga.Ktot >> 6;

  auto stage = [&](int it, int buf) {
    const int k0 = it << 6;
    char* baseA = lds + buf * 32768;
    char* baseB = baseA + 16384;
    #pragma unroll
    for (int j = 0; j < 4; ++j) {
      const __hip_bfloat16* sA = ga.A + (size_t)(bm + rowS[j]) * ga.lda + k0 + (scbS[j] >> 1);
      __builtin_amdgcn_global_load_lds((AS1C)sA, (AS3P)(baseA + dstS[j]), 16, 0, 0);
      const __hip_bfloat16* sB = ga.WT + (size_t)(bn + rowS[j]) * ga.ldk + k0 + (scbS[j] >> 1);
      __builtin_amdgcn_global_load_lds((AS1C)sB, (AS3P)(baseB + dstS[j]), 16, 0, 0);
    }
  };

  auto compute = [&](int buf) {
    const char* baseA = lds + buf * 32768;
    const char* baseB = baseA + 16384;
    #pragma unroll
    for (int kk = 0; kk < 2; ++kk) {
      bf16x8 a[4], b[4];
      int cb = kk * 64 + (lane >> 4) * 16;
      #pragma unroll
      for (int f = 0; f < 4; ++f) {
        int row = wr * 64 + f * 16 + (lane & 15);
        a[f] = *(const bf16x8*)(baseA + row * 128 + (cb ^ ((row & 7) << 4)));
        int nl = wc * 64 + f * 16 + (lane & 15);
        b[f] = *(const bf16x8*)(baseB + nl * 128 + (cb ^ ((nl & 7) << 4)));
      }
      #pragma unroll
      for (int fm = 0; fm < 4; ++fm)
        #pragma unroll
        for (int fn = 0; fn < 4; ++fn)
          acc[fm][fn] = __builtin_amdgcn_mfma_f32_16x16x32_bf16(a[fm], b[fn], acc[fm][fn], 0, 0, 0);
    }
  };

  stage(0, 0);
  stage(1, 1);
  asm volatile("s_waitcnt vmcnt(8)" ::: "memory");
  __builtin_amdgcn_s_barrier();
  int cur = 0;
  for (int i = 0; i < nit; ++i) {
    compute(cur);
    __builtin_amdgcn_s_barrier();
    if (i + 2 < nit) stage(i + 2, cur);
    if (i + 1 < nit) {
      if (i + 2 < nit) asm volatile("s_waitcnt vmcnt(8)" ::: "memory");
      else             asm volatile("s_waitcnt vmcnt(0)" ::: "memory");
      __builtin_amdgcn_s_barrier();
    }
    cur ^= 1;
  }

  #pragma unroll
  for (int fm = 0; fm < 4; ++fm) {
    int rbase = bm + wr * 64 + fm * 16 + (lane >> 4) * 4;
    #pragma unroll
    for (int fn = 0; fn < 4; ++fn) {
      int col = bn + wc * 64 + fn * 16 + (lane & 15);
      if (col >= ga.N) continue;
      float bv = ga.bias ? ga.bias[col] : 0.0f;
      #pragma unroll
      for (int j = 0; j < 4; ++j) {
        float v = acc[fm][fn][j] + bv;
        if (ga.act == 1) v = fmaxf(v, 0.0f);
        int m = rbase + j;
        size_t off = ga.cmap == 1
            ? (size_t)(m & 127) * ga.ldc + (size_t)(m >> 7) * kV + col
            : (size_t)m * ga.ldc + col;
        if (ga.C) ga.C[off] = v;
        if (ga.C16) ga.C16[off] = __float2bfloat16(v);
      }
    }
  }
}

// ------------------------------------------------------- small fused kernels
__global__ __launch_bounds__(256) void mean_p(const float* __restrict__ Vfeat,
                                              __hip_bfloat16* __restrict__ meanVb) {
  int idx = blockIdx.x * 256 + threadIdx.x;
  if (idx >= kB * kH) return;
  int b = idx >> 10, h = idx & 1023;
  float sm = 0.0f;
  for (int p = 0; p < kP; ++p) sm += Vfeat[((size_t)b * kP + p) * kH + h];
  meanVb[idx] = __float2bfloat16(sm * (1.0f / kP));
}

// LSTM1 gates + sentinel + full adaptive-attention step. One block per batch.
// g comes as TWO split-K slabs of [128][5120] raw sums; bias added here.
constexpr int kSlab1 = kB * 5120;
__global__ __launch_bounds__(256) void step1_fused(
    const float* __restrict__ g, const float* __restrict__ bias_g1,
    float* __restrict__ c1, __hip_bfloat16* __restrict__ h1b,
    const float* __restrict__ img_proj, const float* __restrict__ Vfeat,
    const float* __restrict__ Wg, const float* __restrict__ Ws,
    const float* __restrict__ bs, const float* __restrict__ wh,
    float* __restrict__ c_hat, __hip_bfloat16* __restrict__ c_hatb,
    float* __restrict__ out_alphas, float* __restrict__ out_betas, int t) {
  const int b = blockIdx.x;
  const int tid = threadIdx.x;
  const int lane = tid & 63;
  const int w = tid >> 6;
  __shared__ float sh_h1[kH];
  __shared__ float sh_st[kH];
  __shared__ float wsum[4][36];
  __shared__ float htp[36];
  __shared__ float stp[36];
  __shared__ float alpha[kP];
  __shared__ float sred[4];  // 0: att_vs, 1: beta, 2: zmax, 3: zsum

  const float* gr0 = g + (size_t)b * 5120;
  const float* gr1 = gr0 + kSlab1;
  #pragma unroll
  for (int i = 0; i < 4; ++i) {
    int h = tid + i * 256;
    float ig = sigf(gr0[h]           + gr1[h]           + bias_g1[h]);
    float fg = sigf(gr0[kH + h]      + gr1[kH + h]      + bias_g1[kH + h]);
    float gg = tanhf(gr0[2 * kH + h] + gr1[2 * kH + h]  + bias_g1[2 * kH + h]);
    float og = sigf(gr0[3 * kH + h]  + gr1[3 * kH + h]  + bias_g1[3 * kH + h]);
    int idx = b * kH + h;
    float c = fg * c1[idx] + ig * gg;
    float tc = tanhf(c);
    float hn = og * tc;
    c1[idx] = c;
    h1b[idx] = __float2bfloat16(hn);
    sh_h1[h] = hn;
    sh_st[h] = sigf(gr0[4 * kH + h] + gr1[4 * kH + h] + bias_g1[4 * kH + h]) * tc;
  }
  __syncthreads();

  #pragma unroll
  for (int pass = 0; pass < 2; ++pass) {
    const float* vec = pass == 0 ? sh_h1 : sh_st;
    const float* W = pass == 0 ? Wg : Ws;
    float pg[36];
    #pragma unroll
    for (int j = 0; j < 36; ++j) pg[j] = 0.0f;
    #pragma unroll
    for (int i = 0; i < 4; ++i) {
      int hh = tid + i * 256;
      float hv = vec[hh];
      const float4* wrow = reinterpret_cast<const float4*>(W + (size_t)hh * 36);
      #pragma unroll
      for (int r = 0; r < 9; ++r) {
        float4 wv = wrow[r];
        pg[4 * r + 0] = fmaf(hv, wv.x, pg[4 * r + 0]);
        pg[4 * r + 1] = fmaf(hv, wv.y, pg[4 * r + 1]);
        pg[4 * r + 2] = fmaf(hv, wv.z, pg[4 * r + 2]);
        pg[4 * r + 3] = fmaf(hv, wv.w, pg[4 * r + 3]);
      }
    }
    #pragma unroll
    for (int j = 0; j < 36; ++j) {
      float v = pg[j];
      #pragma unroll
      for (int off = 32; off > 0; off >>= 1) v += __shfl_down(v, off, 64);
      if (lane == 0) wsum[w][j] = v;
    }
    __syncthreads();
    if (tid < 36) {
      float s = wsum[0][tid] + wsum[1][tid] + wsum[2][tid] + wsum[3][tid];
      if (pass == 0) htp[tid] = s; else stp[tid] = s;
    }
    __syncthreads();
  }

  if (w == 0) {
    float zz_r = -3.0e38f;
    if (lane < kP) {
      const float* ip = img_proj + ((size_t)b * kP + lane) * kP;
      float acc = 0.0f;
      #pragma unroll
      for (int j = 0; j < kP; ++j) acc = fmaf(tanhf(ip[j] + htp[j]), wh[j], acc);
      zz_r = acc;
    }
    float m = zz_r;
    #pragma unroll
    for (int off = 32; off > 0; off >>= 1) m = fmaxf(m, __shfl_xor(m, off, 64));
    float e = (lane < kP) ? expf(zz_r - m) : 0.0f;
    float s = e;
    #pragma unroll
    for (int off = 32; off > 0; off >>= 1) s += __shfl_xor(s, off, 64);
    if (lane < kP) alpha[lane] = e / s;
    if (lane == 0) { sred[2] = m; sred[3] = s; }
  } else if (w == 1) {
    float tv = 0.0f;
    if (lane < kP) tv = tanhf(stp[lane] + bs[lane] + htp[lane]) * wh[lane];
    #pragma unroll
    for (int off = 32; off > 0; off >>= 1) tv += __shfl_xor(tv, off, 64);
    if (lane == 0) sred[0] = tv;
  }
  __syncthreads();
  if (tid == 0) {
    float av = sred[0], m = sred[2], s = sred[3];
    float m2 = fmaxf(m, av);
    float eb = expf(av - m2);
    float beta = eb / (s * expf(m - m2) + eb);
    sred[1] = beta;
    out_betas[b * kT + t] = beta;
  }
  __syncthreads();
  if (tid < kP) out_alphas[((size_t)b * kT + t) * kP + tid] = alpha[tid];
  const float beta = sred[1];
  #pragma unroll
  for (int i = 0; i < 4; ++i) {
    int h = tid + i * 256;
    float ctx = 0.0f;
    for (int p = 0; p < kP; ++p) ctx = fmaf(alpha[p], Vfeat[((size_t)b * kP + p) * kH + h], ctx);
    float v = beta * sh_st[h] + (1.0f - beta) * ctx;
    c_hat[(size_t)b * kH + h] = v;
    c_hatb[(size_t)b * kH + h] = __float2bfloat16(v);
  }
}

// g: two split-K slabs of [128][4096] raw sums; bias added here.
constexpr int kSlab2 = kB * 4096;
__global__ __launch_bounds__(256) void lstm2_elem(const float* __restrict__ g,
                                                  const float* __restrict__ bias_g2,
                                                  float* __restrict__ c2,
                                                  __hip_bfloat16* __restrict__ h2b,
                                                  const float* __restrict__ c_hat,
                                                  __hip_bfloat16* __restrict__ sbufb) {
  int idx = blockIdx.x * 256 + threadIdx.x;
  if (idx >= kB * kH) return;
  int b = idx >> 10, h = idx & 1023;
  const float* gr0 = g + (size_t)b * 4 * kH;
  const float* gr1 = gr0 + kSlab2;
  float ig = sigf(gr0[h]           + gr1[h]           + bias_g2[h]);
  float fg = sigf(gr0[kH + h]      + gr1[kH + h]      + bias_g2[kH + h]);
  float gg = tanhf(gr0[2 * kH + h] + gr1[2 * kH + h]  + bias_g2[2 * kH + h]);
  float og = sigf(gr0[3 * kH + h]  + gr1[3 * kH + h]  + bias_g2[3 * kH + h]);
  float c = fg * c2[idx] + ig * gg;
  float hn = og * tanhf(c);
  c2[idx] = c;
  h2b[idx] = __float2bfloat16(hn);
  sbufb[idx] = __float2bfloat16(c_hat[idx] + hn);
}

// ------------------------------------------------------------------ launch
extern "C" void kernel_launch(void* const* d_in, const int* in_sizes, int n_in,
                              void* d_out, int out_size, void* d_ws, size_t ws_size,
                              hipStream_t stream) {
  const float* images  = (const float*)d_in[0];
  const int*   caps    = (const int*)d_in[1];
  const float* W_img   = (const float*)d_in[3];
  const float* b_img   = (const float*)d_in[4];
  const float* W_glob  = (const float*)d_in[5];
  const float* b_glob  = (const float*)d_in[6];
  const float* W_ih1   = (const float*)d_in[7];
  const float* W_hh1   = (const float*)d_in[8];
  const float* b_ih1   = (const float*)d_in[9];
  const float* b_hh1   = (const float*)d_in[10];
  const float* Wx_gate = (const float*)d_in[11];
  const float* bx_gate = (const float*)d_in[12];
  const float* Wh_gate = (const float*)d_in[13];
  const float* bh_gate = (const float*)d_in[14];
  const float* W_ih2   = (const float*)d_in[15];
  const float* W_hh2   = (const float*)d_in[16];
  const float* b_ih2   = (const float*)d_in[17];
  const float* b_hh2   = (const float*)d_in[18];
  const float* Wv      = (const float*)d_in[19];
  const float* bv      = (const float*)d_in[20];
  const float* Ws_     = (const float*)d_in[21];
  const float* bs_     = (const float*)d_in[22];
  const float* Wg      = (const float*)d_in[23];
  const float* wh      = (const float*)d_in[24];
  const float* emb     = (const float*)d_in[25];
  const float* W_fc    = (const float*)d_in[26];
  const float* b_fc    = (const float*)d_in[27];

  float* out = (float*)d_out;
  float* out_alphas = out + (size_t)kB * kT * kV;
  float* out_betas  = out_alphas + (size_t)kB * kT * kP;

  char* base = (char*)d_ws;
  auto alloc = [&](size_t bytes) {
    char* p = base;
    base += (bytes + 255) & ~(size_t)255;
    return p;
  };
  float*          Vfeat   = (float*)alloc((size_t)kB * kP * kH * 4);
  __hip_bfloat16* Vfeatb  = (__hip_bfloat16*)alloc((size_t)kB * kP * kH * 2);
  __hip_bfloat16* imagesb = (__hip_bfloat16*)alloc((size_t)kB * kP * kRaw * 2);
  __hip_bfloat16* WTg1    = (__hip_bfloat16*)alloc((size_t)5120 * 3072 * 2);
  __hip_bfloat16* WTg2    = (__hip_bfloat16*)alloc((size_t)4096 * 3072 * 2);
  __hip_bfloat16* WTfc    = (__hip_bfloat16*)alloc((size_t)12032 * 1024 * 2);
  __hip_bfloat16* WTimg   = (__hip_bfloat16*)alloc((size_t)1024 * 2048 * 2);
  __hip_bfloat16* WTglob  = (__hip_bfloat16*)alloc((size_t)512 * 1024 * 2);
  __hip_bfloat16* WTv     = (__hip_bfloat16*)alloc((size_t)64 * 1024 * 2);
  __hip_bfloat16* wembb   = (__hip_bfloat16*)alloc((size_t)kB * kT * kE * 2);
  float*          img_proj= (float*)alloc((size_t)kB * kP * kP * 4);
  __hip_bfloat16* globb   = (__hip_bfloat16*)alloc((size_t)kB * kE * 2);
  __hip_bfloat16* meanVb  = (__hip_bfloat16*)alloc((size_t)kB * kH * 2);
  float*          c1      = (float*)alloc((size_t)2 * kB * kH * 4);  // c1, c2
  float*          c2      = c1 + kB * kH;
  __hip_bfloat16* h1b     = (__hip_bfloat16*)alloc((size_t)2 * kB * kH * 2);
  __hip_bfloat16* h2b     = h1b + kB * kH;
  float*          g1out   = (float*)alloc((size_t)2 * kB * 5120 * 4);  // 2 slabs
  float*          chat    = (float*)alloc((size_t)kB * kH * 4);
  __hip_bfloat16* chatb   = (__hip_bfloat16*)alloc((size_t)kB * kH * 2);
  __hip_bfloat16* sbufall = (__hip_bfloat16*)alloc((size_t)kT * kB * kH * 2);  // [t][b][h]
  float*          bias_g1 = (float*)alloc(5120 * 4);
  float*          bias_g2 = (float*)alloc(4096 * 4);

  // ---- merged prep (1 launch)
  {
    long total = (long)NZ1 + NZ2 + NCV + NPV + NPF + NPB + NGE;
    int blocks = (int)((total + 255) / 256);
    prep_small<<<blocks, 256, 0, stream>>>(
        c1, (uint4*)h1b, images, imagesb, (uint4*)WTv,
        (uint4*)(WTfc + (size_t)12000 * 1024),
        b_ih1, b_hh1, bx_gate, bh_gate, b_ih2, b_hh2, bias_g1, bias_g2,
        caps, emb, wembb);
  }
  // ---- merged transposes (1 launch)
  {
    TAll ta = {};
    int off = 0, j = 0;
    auto add = [&](const float* src, int ldsrc, int K, int N, __hip_bfloat16* dst,
                   int lddst, int koff, int noff) {
      int nbx = (N + 31) / 32, nby = (K + 31) / 32;
      ta.job[j] = {src, dst, ldsrc, K, N, lddst, koff, noff, off, nbx};
      off += nbx * nby;
      ++j;
    };
    add(W_img,   kH,     kRaw, kH,     WTimg,  kRaw, 0, 0);
    add(W_glob,  kE,     kH,   kE,     WTglob, kH,   0, 0);
    add(Wv,      kP,     kH,   kP,     WTv,    kH,   0, 0);
    add(W_ih1,   4 * kH, 2048, 4 * kH, WTg1,   3072, 0, 0);
    add(W_hh1,   4 * kH, 1024, 4 * kH, WTg1,   3072, 2048, 0);
    add(Wx_gate, kH,     2048, kH,     WTg1,   3072, 0, 4096);
    add(Wh_gate, kH,     1024, kH,     WTg1,   3072, 2048, 4096);
    add(W_ih2,   4 * kH, 2048, 4 * kH, WTg2,   3072, 0, 0);
    add(W_hh2,   4 * kH, 1024, 4 * kH, WTg2,   3072, 2048, 0);
    add(W_fc,    kV,     kH,   kV,     WTfc,   kH,   0, 0);
    ta.njobs = j;
    ta.total_blocks = off;
    transpose_all<<<off, 256, 0, stream>>>(ta);
  }

  // Vfeat = relu(images @ W_img + b_img)   [4608 x 1024], K=2048  (128^2 tile)
  {
    G128Args ga = {};
    ga.A = imagesb; ga.lda = kRaw; ga.WT = WTimg; ga.ldk = kRaw; ga.bias = b_img;
    ga.C = Vfeat; ga.C16 = Vfeatb; ga.ldc = kH; ga.N = kH; ga.Ktot = kRaw;
    ga.act = 1; ga.cmap = 0;
    gemm128<<<dim3(kH / 128, kB * kP / 128), 256, 0, stream>>>(ga);
  }
  mean_p<<<(kB * kH + 255) / 256, 256, 0, stream>>>(Vfeat, meanVb);
  // glob = relu(meanV @ W_glob + b_glob)
  {
    GemmBArgs ga = {};
    ga.seg[0] = {meanVb, kH, 0, kH};
    ga.nseg = 1; ga.WT = WTglob; ga.ldk = kH; ga.bias = b_glob;
    ga.C = nullptr; ga.C16 = globb; ga.ldc = kE; ga.N = kE; ga.Ktot = kH; ga.act = 1;
    gemm_bf16<<<dim3(kE / 64, kB / 64, 1), 256, 0, stream>>>(ga);
  }
  // img_proj = Vfeat @ Wv + bv
  {
    GemmBArgs ga = {};
    ga.seg[0] = {Vfeatb, kH, 0, kH};
    ga.nseg = 1; ga.WT = WTv; ga.ldk = kH; ga.bias = bv;
    ga.C = img_proj; ga.C16 = nullptr; ga.ldc = kP; ga.N = kP; ga.Ktot = kH; ga.act = 0;
    gemm_bf16<<<dim3(1, kB * kP / 64, 1), 256, 0, stream>>>(ga);
  }

  // ---- 20 decode steps (4 kernels each; fc deferred)
  for (int t = 0; t < kT; ++t) {
    {  // g1 + sentinel: [128 x 5120], K = 3072, split-K=2
      GemmBArgs ga = {};
      ga.seg[0] = {h2b, kH, 0, kH};
      ga.seg[1] = {globb, kE, kH, kH + kE};
      ga.seg[2] = {wembb + (size_t)t * kE, kT * kE, kH + kE, 2048};
      ga.seg[3] = {h1b, kH, 2048, 3072};
      ga.nseg = 4; ga.WT = WTg1; ga.ldk = 3072; ga.bias = nullptr;
      ga.C = g1out; ga.C16 = nullptr; ga.ldc = 5120; ga.N = 5120; ga.Ktot = 3072;
      ga.act = 0; ga.zstride = kSlab1;
      gemm_bf16<<<dim3(5120 / 64, kB / 64, 2), 256, 0, stream>>>(ga);
    }
    step1_fused<<<kB, 256, 0, stream>>>(g1out, bias_g1, c1, h1b, img_proj, Vfeat,
                                        Wg, Ws_, bs_, wh, chat, chatb,
                                        out_alphas, out_betas, t);
    {  // g2: [128 x 4096], K = 3072, split-K=2
      GemmBArgs ga = {};
      ga.seg[0] = {chatb, kH, 0, kH};
      ga.seg[1] = {h1b, kH, kH, 2048};
      ga.seg[2] = {h2b, kH, 2048, 3072};
      ga.nseg = 3; ga.WT = WTg2; ga.ldk = 3072; ga.bias = nullptr;
      ga.C = g1out; ga.C16 = nullptr; ga.ldc = 4096; ga.N = 4096; ga.Ktot = 3072;
      ga.act = 0; ga.zstride = kSlab2;
      gemm_bf16<<<dim3(4096 / 64, kB / 64, 2), 256, 0, stream>>>(ga);
    }
    lstm2_elem<<<(kB * kH + 255) / 256, 256, 0, stream>>>(
        g1out, bias_g2, c2, h2b, chat, sbufall + (size_t)t * kB * kH);
  }

  // ---- batched fc over all steps: [2560 x 12000], K = 1024  (128^2 tile)
  {
    G128Args ga = {};
    ga.A = sbufall; ga.lda = kH; ga.WT = WTfc; ga.ldk = kH; ga.bias = b_fc;
    ga.C = out; ga.C16 = nullptr; ga.ldc = kT * kV; ga.N = kV; ga.Ktot = kH;
    ga.act = 0; ga.cmap = 1;
    gemm128<<<dim3(12032 / 128, kT * kB / 128), 256, 0, stream>>>(ga);
  }
}

// Round 9
// 1585.244 us; speedup vs baseline: 1.4078x; 1.0016x over previous
//
#include <hip/hip_runtime.h>
#include <hip/hip_bf16.h>
#include <math.h>

typedef __attribute__((ext_vector_type(4))) float f32x4;
typedef __attribute__((ext_vector_type(8))) short bf16x8;

constexpr int kB = 128, kT = 20, kH = 1024, kE = 512, kP = 36, kRaw = 2048, kV = 12000;

__device__ __forceinline__ float sigf(float x) { return 1.0f / (1.0f + expf(-x)); }

#define AS1C const __attribute__((address_space(1))) void*
#define AS3P __attribute__((address_space(3))) void*

// ---------------------------------------------------------------- merged prep
constexpr int NZ1 = 2 * kB * kH / 4;        // float4 zeros over c1,c2
constexpr int NZ2 = 2 * kB * kH * 2 / 16;   // uint4 zeros over h1b,h2b
constexpr int NCV = kB * kP * kRaw / 4;     // images -> bf16 (4 per thread)
constexpr int NPV = 64 * 1024 * 2 / 16;     // WTv zero (uint4)
constexpr int NPF = 32 * 1024 * 2 / 16;     // WTfc pad zero (uint4)
constexpr int NPB = 5120;                   // pack biases
constexpr int NGE = kB * kT * kE;           // gather embeddings

__global__ __launch_bounds__(256) void prep_small(
    float* c1z, uint4* h1z, const float* images, __hip_bfloat16* imagesb,
    uint4* wtv, uint4* wtfc_pad,
    const float* b_ih1, const float* b_hh1, const float* bx, const float* bh,
    const float* b_ih2, const float* b_hh2, float* bias_g1, float* bias_g2,
    const int* caps, const float* emb, __hip_bfloat16* wembb) {
  long idx = (long)blockIdx.x * 256 + threadIdx.x;
  if (idx < NZ1) { reinterpret_cast<float4*>(c1z)[idx] = make_float4(0, 0, 0, 0); return; }
  idx -= NZ1;
  if (idx < NZ2) { h1z[idx] = make_uint4(0, 0, 0, 0); return; }
  idx -= NZ2;
  if (idx < NCV) {
    float4 v = reinterpret_cast<const float4*>(images)[idx];
    __hip_bfloat16* d = imagesb + idx * 4;
    d[0] = __float2bfloat16(v.x); d[1] = __float2bfloat16(v.y);
    d[2] = __float2bfloat16(v.z); d[3] = __float2bfloat16(v.w);
    return;
  }
  idx -= NCV;
  if (idx < NPV) { wtv[idx] = make_uint4(0, 0, 0, 0); return; }
  idx -= NPV;
  if (idx < NPF) { wtfc_pad[idx] = make_uint4(0, 0, 0, 0); return; }
  idx -= NPF;
  if (idx < NPB) {
    int i = (int)idx;
    if (i < 4096) {
      bias_g1[i] = b_ih1[i] + b_hh1[i];
      bias_g2[i] = b_ih2[i] + b_hh2[i];
    } else {
      bias_g1[i] = bx[i - 4096] + bh[i - 4096];
    }
    return;
  }
  idx -= NPB;
  if (idx < NGE) {
    int e = (int)(idx % kE);
    int bt = (int)(idx / kE);
    int t = bt % kT;
    int b = bt / kT;
    int tok = caps[b * (kT + 1) + t];
    wembb[idx] = __float2bfloat16(emb[(size_t)tok * kE + e]);
  }
}

// Astat[t*128+b][1024] = [ globb[b] | wembb[b][t] ]  (bf16, uint4 = 8 elems)
__global__ __launch_bounds__(256) void build_astat(const __hip_bfloat16* __restrict__ globb,
                                                   const __hip_bfloat16* __restrict__ wembb,
                                                   uint4* __restrict__ astat) {
  int idx = blockIdx.x * 256 + threadIdx.x;
  if (idx >= kT * kB * 1024 / 8) return;
  int m = idx >> 7;            // 128 uint4 per row
  int c = (idx & 127) * 8;
  int b = m & 127, t = m >> 7;
  const __hip_bfloat16* src = (c < 512)
      ? globb + b * 512 + c
      : wembb + ((size_t)(b * kT + t)) * 512 + (c - 512);
  astat[idx] = *reinterpret_cast<const uint4*>(src);
}

// ------------------------------------------------ merged weight transposes
struct TJob {
  const float* src; __hip_bfloat16* dst;
  int ld_src, K, N, lddst, koff, noff, blk_off, nbx;
};
struct TAll { TJob job[12]; int njobs; int total_blocks; };

__global__ __launch_bounds__(256) void transpose_all(TAll ta) {
  __shared__ float t[32][33];
  int bid = blockIdx.x;
  int ji = 0;
  while (ji + 1 < ta.njobs && bid >= ta.job[ji + 1].blk_off) ++ji;
  const TJob& J = ta.job[ji];
  int lbid = bid - J.blk_off;
  int n0 = (lbid % J.nbx) * 32, k0 = (lbid / J.nbx) * 32;
  int tx = threadIdx.x & 31, ty = threadIdx.x >> 5;  // 32 x 8
  #pragma unroll
  for (int i = 0; i < 32; i += 8) {
    int k = k0 + ty + i, n = n0 + tx;
    t[ty + i][tx] = (k < J.K && n < J.N) ? J.src[(size_t)k * J.ld_src + n] : 0.0f;
  }
  __syncthreads();
  #pragma unroll
  for (int i = 0; i < 32; i += 8) {
    int n = n0 + ty + i, k = k0 + tx;
    if (n < J.N && k < J.K)
      J.dst[(size_t)(n + J.noff) * J.lddst + k + J.koff] = __float2bfloat16(t[tx][ty + i]);
  }
}

// ------------------------------------------------------- 64x64 bf16 MFMA GEMM
// BK=128, 2-buffer counted-vmcnt pipeline. Split-K via gridDim.z.
struct SegB { const __hip_bfloat16* A; int lda; int kstart; int kend; };
struct GemmBArgs {
  SegB seg[4]; int nseg;
  const __hip_bfloat16* WT; int ldk;
  const float* bias;
  float* C; __hip_bfloat16* C16; int ldc; int N; int Ktot; int act; int zstride;
};

__global__ __launch_bounds__(256) void gemm_bf16(GemmBArgs ga) {
  __shared__ char lds[65536];  // 2 bufs x (A 16K | B 16K)
  const int bm = blockIdx.y * 64;
  const int bn = blockIdx.x * 64;
  const int tid = threadIdx.x;
  const int lane = tid & 63;
  const int w = tid >> 6;
  const int wr = w >> 1, wc = w & 1;

  int rowS[4], scbS[4], dstS[4];
  #pragma unroll
  for (int j = 0; j < 4; ++j) {
    int off = ((j * 4 + w) * 64 + lane) * 16;   // linear byte in 16 KB tile
    int row = off >> 8, colb = off & 255;       // 256 B rows (BK=128)
    rowS[j] = row;
    scbS[j] = colb ^ ((row & 7) << 4);
    dstS[j] = (j * 4 + w) * 1024;
  }

  f32x4 acc[2][2] = {};
  const int nz = gridDim.z;
  const int nit = (ga.Ktot >> 7) / nz;
  const int it0 = blockIdx.z * nit;
  float* C = ga.C + (size_t)blockIdx.z * ga.zstride;

  auto stage = [&](int it, int buf) {
    const int k0 = it << 7;
    int si = 0;
    while (k0 >= ga.seg[si].kend) ++si;
    const __hip_bfloat16* Aseg = ga.seg[si].A;
    const int lda = ga.seg[si].lda;
    const int ks = k0 - ga.seg[si].kstart;
    char* baseA = lds + buf * 32768;
    char* baseB = baseA + 16384;
    #pragma unroll
    for (int j = 0; j < 4; ++j) {
      const __hip_bfloat16* sA = Aseg + (size_t)(bm + rowS[j]) * lda + ks + (scbS[j] >> 1);
      __builtin_amdgcn_global_load_lds((AS1C)sA, (AS3P)(baseA + dstS[j]), 16, 0, 0);
      const __hip_bfloat16* sB = ga.WT + (size_t)(bn + rowS[j]) * ga.ldk + k0 + (scbS[j] >> 1);
      __builtin_amdgcn_global_load_lds((AS1C)sB, (AS3P)(baseB + dstS[j]), 16, 0, 0);
    }
  };

  auto compute = [&](int buf) {
    const char* baseA = lds + buf * 32768;
    const char* baseB = baseA + 16384;
    #pragma unroll
    for (int kk = 0; kk < 4; ++kk) {
      bf16x8 a[2], b[2];
      #pragma unroll
      for (int f = 0; f < 2; ++f) {
        int row = wr * 32 + f * 16 + (lane & 15);
        int cb = kk * 64 + (lane >> 4) * 16;
        a[f] = *(const bf16x8*)(baseA + row * 256 + (cb ^ ((row & 7) << 4)));
        int nl = wc * 32 + f * 16 + (lane & 15);
        b[f] = *(const bf16x8*)(baseB + nl * 256 + (cb ^ ((nl & 7) << 4)));
      }
      #pragma unroll
      for (int fm = 0; fm < 2; ++fm)
        #pragma unroll
        for (int fn = 0; fn < 2; ++fn)
          acc[fm][fn] = __builtin_amdgcn_mfma_f32_16x16x32_bf16(a[fm], b[fn], acc[fm][fn], 0, 0, 0);
    }
  };

  stage(it0, 0);
  stage(it0 + 1, 1);
  asm volatile("s_waitcnt vmcnt(8)" ::: "memory");
  __builtin_amdgcn_s_barrier();
  int cur = 0;
  for (int i = 0; i < nit; ++i) {
    compute(cur);
    __builtin_amdgcn_s_barrier();
    if (i + 2 < nit) stage(it0 + i + 2, cur);
    if (i + 1 < nit) {
      if (i + 2 < nit) asm volatile("s_waitcnt vmcnt(8)" ::: "memory");
      else             asm volatile("s_waitcnt vmcnt(0)" ::: "memory");
      __builtin_amdgcn_s_barrier();
    }
    cur ^= 1;
  }

  #pragma unroll
  for (int fm = 0; fm < 2; ++fm) {
    int rbase = bm + wr * 32 + fm * 16 + (lane >> 4) * 4;
    #pragma unroll
    for (int fn = 0; fn < 2; ++fn) {
      int col = bn + wc * 32 + fn * 16 + (lane & 15);
      if (col >= ga.N) continue;
      float bv = ga.bias ? ga.bias[col] : 0.0f;
      #pragma unroll
      for (int j = 0; j < 4; ++j) {
        float v = acc[fm][fn][j] + bv;
        if (ga.act == 1) v = fmaxf(v, 0.0f);
        size_t off = (size_t)(rbase + j) * ga.ldc + col;
        if (ga.C) C[off] = v;
        if (ga.C16) ga.C16[off] = __float2bfloat16(v);
      }
    }
  }
}

// ------------------------------------------- 128x128 m97-structure bf16 GEMM
// BK=64, 4 waves x (64x64), acc 4x4, 2-buffer counted vmcnt, XCD swizzle.
// morder==1: bm-fastest within XCD chunk (B column-stripe stays L2-resident).
// cmap==1: row m -> C[(m&127)*ldc + (m>>7)*kV + col].
struct G128Args {
  const __hip_bfloat16* A; int lda;
  const __hip_bfloat16* WT; int ldk;
  const float* bias;
  float* C; __hip_bfloat16* C16; int ldc; int N; int Ktot; int act; int cmap; int morder;
};

__global__ __launch_bounds__(256) void gemm128(G128Args ga) {
  __shared__ char lds[65536];  // 2 bufs x (A 16K | B 16K)
  const int gx = gridDim.x;
  const int gy = gridDim.y;
  const int nwg = gx * gy;
  int bid = blockIdx.y * gx + blockIdx.x;
  int q = nwg >> 3, r = nwg & 7;
  int xc = bid & 7, yq = bid >> 3;
  int swz = (xc < r ? xc * (q + 1) : r * (q + 1) + (xc - r) * q) + yq;
  int bn, bm;
  if (ga.morder == 1) { bm = (swz % gy) * 128; bn = (swz / gy) * 128; }
  else                { bn = (swz % gx) * 128; bm = (swz / gx) * 128; }

  const int tid = threadIdx.x;
  const int lane = tid & 63;
  const int w = tid >> 6;
  const int wr = w >> 1, wc = w & 1;

  int rowS[4], scbS[4], dstS[4];
  #pragma unroll
  for (int j = 0; j < 4; ++j) {
    int off = ((j * 4 + w) * 64 + lane) * 16;   // linear byte in 16 KB tile
    int row = off >> 7, colb = off & 127;       // 128 B rows (BK=64)
    rowS[j] = row;
    scbS[j] = colb ^ ((row & 7) << 4);
    dstS[j] = (j * 4 + w) * 1024;
  }

  f32x4 acc[4][4] = {};
  const int nit = ga.Ktot >> 6;

  auto stage = [&](int it, int buf) {
    const int k0 = it << 6;
    char* baseA = lds + buf * 32768;
    char* baseB = baseA + 16384;
    #pragma unroll
    for (int j = 0; j < 4; ++j) {
      const __hip_bfloat16* sA = ga.A + (size_t)(bm + rowS[j]) * ga.lda + k0 + (scbS[j] >> 1);
      __builtin_amdgcn_global_load_lds((AS1C)sA, (AS3P)(baseA + dstS[j]), 16, 0, 0);
      const __hip_bfloat16* sB = ga.WT + (size_t)(bn + rowS[j]) * ga.ldk + k0 + (scbS[j] >> 1);
      __builtin_amdgcn_global_load_lds((AS1C)sB, (AS3P)(baseB + dstS[j]), 16, 0, 0);
    }
  };

  auto compute = [&](int buf) {
    const char* baseA = lds + buf * 32768;
    const char* baseB = baseA + 16384;
    #pragma unroll
    for (int kk = 0; kk < 2; ++kk) {
      bf16x8 a[4], b[4];
      int cb = kk * 64 + (lane >> 4) * 16;
      #pragma unroll
      for (int f = 0; f < 4; ++f) {
        int row = wr * 64 + f * 16 + (lane & 15);
        a[f] = *(const bf16x8*)(baseA + row * 128 + (cb ^ ((row & 7) << 4)));
        int nl = wc * 64 + f * 16 + (lane & 15);
        b[f] = *(const bf16x8*)(baseB + nl * 128 + (cb ^ ((nl & 7) << 4)));
      }
      #pragma unroll
      for (int fm = 0; fm < 4; ++fm)
        #pragma unroll
        for (int fn = 0; fn < 4; ++fn)
          acc[fm][fn] = __builtin_amdgcn_mfma_f32_16x16x32_bf16(a[fm], b[fn], acc[fm][fn], 0, 0, 0);
    }
  };

  stage(0, 0);
  stage(1, 1);
  asm volatile("s_waitcnt vmcnt(8)" ::: "memory");
  __builtin_amdgcn_s_barrier();
  int cur = 0;
  for (int i = 0; i < nit; ++i) {
    compute(cur);
    __builtin_amdgcn_s_barrier();
    if (i + 2 < nit) stage(i + 2, cur);
    if (i + 1 < nit) {
      if (i + 2 < nit) asm volatile("s_waitcnt vmcnt(8)" ::: "memory");
      else             asm volatile("s_waitcnt vmcnt(0)" ::: "memory");
      __builtin_amdgcn_s_barrier();
    }
    cur ^= 1;
  }

  #pragma unroll
  for (int fm = 0; fm < 4; ++fm) {
    int rbase = bm + wr * 64 + fm * 16 + (lane >> 4) * 4;
    #pragma unroll
    for (int fn = 0; fn < 4; ++fn) {
      int col = bn + wc * 64 + fn * 16 + (lane & 15);
      if (col >= ga.N) continue;
      float bv = ga.bias ? ga.bias[col] : 0.0f;
      #pragma unroll
      for (int j = 0; j < 4; ++j) {
        float v = acc[fm][fn][j] + bv;
        if (ga.act == 1) v = fmaxf(v, 0.0f);
        int m = rbase + j;
        size_t off = ga.cmap == 1
            ? (size_t)(m & 127) * ga.ldc + (size_t)(m >> 7) * kV + col
            : (size_t)m * ga.ldc + col;
        if (ga.C) ga.C[off] = v;
        if (ga.C16) ga.C16[off] = __float2bfloat16(v);
      }
    }
  }
}

// ------------------------------------------------------- small fused kernels
__global__ __launch_bounds__(256) void mean_p(const float* __restrict__ Vfeat,
                                              __hip_bfloat16* __restrict__ meanVb) {
  int idx = blockIdx.x * 256 + threadIdx.x;
  if (idx >= kB * kH) return;
  int b = idx >> 10, h = idx & 1023;
  float sm = 0.0f;
  for (int p = 0; p < kP; ++p) sm += Vfeat[((size_t)b * kP + p) * kH + h];
  meanVb[idx] = __float2bfloat16(sm * (1.0f / kP));
}

// LSTM1 gates + sentinel + full adaptive-attention step. One block per batch.
// gate preact = slab0 + slab1 + g1static (static part includes bias).
constexpr int kSlab1 = kB * 5120;
__global__ __launch_bounds__(256) void step1_fused(
    const float* __restrict__ g, const float* __restrict__ gstat,
    float* __restrict__ c1, __hip_bfloat16* __restrict__ h1b,
    const float* __restrict__ img_proj, const float* __restrict__ Vfeat,
    const float* __restrict__ Wg, const float* __restrict__ Ws,
    const float* __restrict__ bs, const float* __restrict__ wh,
    float* __restrict__ c_hat, __hip_bfloat16* __restrict__ c_hatb,
    float* __restrict__ out_alphas, float* __restrict__ out_betas, int t) {
  const int b = blockIdx.x;
  const int tid = threadIdx.x;
  const int lane = tid & 63;
  const int w = tid >> 6;
  __shared__ float sh_h1[kH];
  __shared__ float sh_st[kH];
  __shared__ float wsum[4][36];
  __shared__ float htp[36];
  __shared__ float stp[36];
  __shared__ float alpha[kP];
  __shared__ float sred[4];  // 0: att_vs, 1: beta, 2: zmax, 3: zsum

  const float* gr0 = g + (size_t)b * 5120;
  const float* gr1 = gr0 + kSlab1;
  const float* gs  = gstat + ((size_t)t * kB + b) * 5120;
  #pragma unroll
  for (int i = 0; i < 4; ++i) {
    int h = tid + i * 256;
    float ig = sigf(gr0[h]           + gr1[h]           + gs[h]);
    float fg = sigf(gr0[kH + h]      + gr1[kH + h]      + gs[kH + h]);
    float gg = tanhf(gr0[2 * kH + h] + gr1[2 * kH + h]  + gs[2 * kH + h]);
    float og = sigf(gr0[3 * kH + h]  + gr1[3 * kH + h]  + gs[3 * kH + h]);
    int idx = b * kH + h;
    float c = fg * c1[idx] + ig * gg;
    float tc = tanhf(c);
    float hn = og * tc;
    c1[idx] = c;
    h1b[idx] = __float2bfloat16(hn);
    sh_h1[h] = hn;
    sh_st[h] = sigf(gr0[4 * kH + h] + gr1[4 * kH + h] + gs[4 * kH + h]) * tc;
  }
  __syncthreads();

  #pragma unroll
  for (int pass = 0; pass < 2; ++pass) {
    const float* vec = pass == 0 ? sh_h1 : sh_st;
    const float* W = pass == 0 ? Wg : Ws;
    float pg[36];
    #pragma unroll
    for (int j = 0; j < 36; ++j) pg[j] = 0.0f;
    #pragma unroll
    for (int i = 0; i < 4; ++i) {
      int hh = tid + i * 256;
      float hv = vec[hh];
      const float4* wrow = reinterpret_cast<const float4*>(W + (size_t)hh * 36);
      #pragma unroll
      for (int r = 0; r < 9; ++r) {
        float4 wv = wrow[r];
        pg[4 * r + 0] = fmaf(hv, wv.x, pg[4 * r + 0]);
        pg[4 * r + 1] = fmaf(hv, wv.y, pg[4 * r + 1]);
        pg[4 * r + 2] = fmaf(hv, wv.z, pg[4 * r + 2]);
        pg[4 * r + 3] = fmaf(hv, wv.w, pg[4 * r + 3]);
      }
    }
    #pragma unroll
    for (int j = 0; j < 36; ++j) {
      float v = pg[j];
      #pragma unroll
      for (int off = 32; off > 0; off >>= 1) v += __shfl_down(v, off, 64);
      if (lane == 0) wsum[w][j] = v;
    }
    __syncthreads();
    if (tid < 36) {
      float s = wsum[0][tid] + wsum[1][tid] + wsum[2][tid] + wsum[3][tid];
      if (pass == 0) htp[tid] = s; else stp[tid] = s;
    }
    __syncthreads();
  }

  if (w == 0) {
    float zz_r = -3.0e38f;
    if (lane < kP) {
      const float* ip = img_proj + ((size_t)b * kP + lane) * kP;
      float acc = 0.0f;
      #pragma unroll
      for (int j = 0; j < kP; ++j) acc = fmaf(tanhf(ip[j] + htp[j]), wh[j], acc);
      zz_r = acc;
    }
    float m = zz_r;
    #pragma unroll
    for (int off = 32; off > 0; off >>= 1) m = fmaxf(m, __shfl_xor(m, off, 64));
    float e = (lane < kP) ? expf(zz_r - m) : 0.0f;
    float s = e;
    #pragma unroll
    for (int off = 32; off > 0; off >>= 1) s += __shfl_xor(s, off, 64);
    if (lane < kP) alpha[lane] = e / s;
    if (lane == 0) { sred[2] = m; sred[3] = s; }
  } else if (w == 1) {
    float tv = 0.0f;
    if (lane < kP) tv = tanhf(stp[lane] + bs[lane] + htp[lane]) * wh[lane];
    #pragma unroll
    for (int off = 32; off > 0; off >>= 1) tv += __shfl_xor(tv, off, 64);
    if (lane == 0) sred[0] = tv;
  }
  __syncthreads();
  if (tid == 0) {
    float av = sred[0], m = sred[2], s = sred[3];
    float m2 = fmaxf(m, av);
    float eb = expf(av - m2);
    float beta = eb / (s * expf(m - m2) + eb);
    sred[1] = beta;
    out_betas[b * kT + t] = beta;
  }
  __syncthreads();
  if (tid < kP) out_alphas[((size_t)b * kT + t) * kP + tid] = alpha[tid];
  const float beta = sred[1];
  #pragma unroll
  for (int i = 0; i < 4; ++i) {
    int h = tid + i * 256;
    float ctx = 0.0f;
    for (int p = 0; p < kP; ++p) ctx = fmaf(alpha[p], Vfeat[((size_t)b * kP + p) * kH + h], ctx);
    float v = beta * sh_st[h] + (1.0f - beta) * ctx;
    c_hat[(size_t)b * kH + h] = v;
    c_hatb[(size_t)b * kH + h] = __float2bfloat16(v);
  }
}

// g: two split-K slabs of [128][4096] raw sums; bias added here.
constexpr int kSlab2 = kB * 4096;
__global__ __launch_bounds__(256) void lstm2_elem(const float* __restrict__ g,
                                                  const float* __restrict__ bias_g2,
                                                  float* __restrict__ c2,
                                                  __hip_bfloat16* __restrict__ h2b,
                                                  const float* __restrict__ c_hat,
                                                  __hip_bfloat16* __restrict__ sbufb) {
  int idx = blockIdx.x * 256 + threadIdx.x;
  if (idx >= kB * kH) return;
  int b = idx >> 10, h = idx & 1023;
  const float* gr0 = g + (size_t)b * 4 * kH;
  const float* gr1 = gr0 + kSlab2;
  float ig = sigf(gr0[h]           + gr1[h]           + bias_g2[h]);
  float fg = sigf(gr0[kH + h]      + gr1[kH + h]      + bias_g2[kH + h]);
  float gg = tanhf(gr0[2 * kH + h] + gr1[2 * kH + h]  + bias_g2[2 * kH + h]);
  float og = sigf(gr0[3 * kH + h]  + gr1[3 * kH + h]  + bias_g2[3 * kH + h]);
  float c = fg * c2[idx] + ig * gg;
  float hn = og * tanhf(c);
  c2[idx] = c;
  h2b[idx] = __float2bfloat16(hn);
  sbufb[idx] = __float2bfloat16(c_hat[idx] + hn);
}

// ------------------------------------------------------------------ launch
extern "C" void kernel_launch(void* const* d_in, const int* in_sizes, int n_in,
                              void* d_out, int out_size, void* d_ws, size_t ws_size,
                              hipStream_t stream) {
  const float* images  = (const float*)d_in[0];
  const int*   caps    = (const int*)d_in[1];
  const float* W_img   = (const float*)d_in[3];
  const float* b_img   = (const float*)d_in[4];
  const float* W_glob  = (const float*)d_in[5];
  const float* b_glob  = (const float*)d_in[6];
  const float* W_ih1   = (const float*)d_in[7];
  const float* W_hh1   = (const float*)d_in[8];
  const float* b_ih1   = (const float*)d_in[9];
  const float* b_hh1   = (const float*)d_in[10];
  const float* Wx_gate = (const float*)d_in[11];
  const float* bx_gate = (const float*)d_in[12];
  const float* Wh_gate = (const float*)d_in[13];
  const float* bh_gate = (const float*)d_in[14];
  const float* W_ih2   = (const float*)d_in[15];
  const float* W_hh2   = (const float*)d_in[16];
  const float* b_ih2   = (const float*)d_in[17];
  const float* b_hh2   = (const float*)d_in[18];
  const float* Wv      = (const float*)d_in[19];
  const float* bv      = (const float*)d_in[20];
  const float* Ws_     = (const float*)d_in[21];
  const float* bs_     = (const float*)d_in[22];
  const float* Wg      = (const float*)d_in[23];
  const float* wh      = (const float*)d_in[24];
  const float* emb     = (const float*)d_in[25];
  const float* W_fc    = (const float*)d_in[26];
  const float* b_fc    = (const float*)d_in[27];

  float* out = (float*)d_out;
  float* out_alphas = out + (size_t)kB * kT * kV;
  float* out_betas  = out_alphas + (size_t)kB * kT * kP;

  char* base = (char*)d_ws;
  auto alloc = [&](size_t bytes) {
    char* p = base;
    base += (bytes + 255) & ~(size_t)255;
    return p;
  };
  float*          Vfeat   = (float*)alloc((size_t)kB * kP * kH * 4);
  __hip_bfloat16* Vfeatb  = (__hip_bfloat16*)alloc((size_t)kB * kP * kH * 2);
  __hip_bfloat16* imagesb = (__hip_bfloat16*)alloc((size_t)kB * kP * kRaw * 2);
  __hip_bfloat16* WTg1d   = (__hip_bfloat16*)alloc((size_t)5120 * 2048 * 2);
  __hip_bfloat16* WTg1s   = (__hip_bfloat16*)alloc((size_t)5120 * 1024 * 2);
  __hip_bfloat16* WTg2    = (__hip_bfloat16*)alloc((size_t)4096 * 3072 * 2);
  __hip_bfloat16* WTfc    = (__hip_bfloat16*)alloc((size_t)12032 * 1024 * 2);
  __hip_bfloat16* WTimg   = (__hip_bfloat16*)alloc((size_t)1024 * 2048 * 2);
  __hip_bfloat16* WTglob  = (__hip_bfloat16*)alloc((size_t)512 * 1024 * 2);
  __hip_bfloat16* WTv     = (__hip_bfloat16*)alloc((size_t)64 * 1024 * 2);
  __hip_bfloat16* wembb   = (__hip_bfloat16*)alloc((size_t)kB * kT * kE * 2);
  float*          img_proj= (float*)alloc((size_t)kB * kP * kP * 4);
  __hip_bfloat16* globb   = (__hip_bfloat16*)alloc((size_t)kB * kE * 2);
  __hip_bfloat16* meanVb  = (__hip_bfloat16*)alloc((size_t)kB * kH * 2);
  float*          c1      = (float*)alloc((size_t)2 * kB * kH * 4);  // c1, c2
  float*          c2      = c1 + kB * kH;
  __hip_bfloat16* h1b     = (__hip_bfloat16*)alloc((size_t)2 * kB * kH * 2);
  __hip_bfloat16* h2b     = h1b + kB * kH;
  float*          g1out   = (float*)alloc((size_t)2 * kB * 5120 * 4);  // 2 slabs
  float*          chat    = (float*)alloc((size_t)kB * kH * 4);
  __hip_bfloat16* chatb   = (__hip_bfloat16*)alloc((size_t)kB * kH * 2);
  __hip_bfloat16* sbufall = (__hip_bfloat16*)alloc((size_t)kT * kB * kH * 2);  // [t][b][h]
  __hip_bfloat16* Astat   = (__hip_bfloat16*)alloc((size_t)kT * kB * 1024 * 2);
  float*          g1stat  = (float*)alloc((size_t)kT * kB * 5120 * 4);
  float*          bias_g1 = (float*)alloc(5120 * 4);
  float*          bias_g2 = (float*)alloc(4096 * 4);

  // ---- merged prep (1 launch)
  {
    long total = (long)NZ1 + NZ2 + NCV + NPV + NPF + NPB + NGE;
    int blocks = (int)((total + 255) / 256);
    prep_small<<<blocks, 256, 0, stream>>>(
        c1, (uint4*)h1b, images, imagesb, (uint4*)WTv,
        (uint4*)(WTfc + (size_t)12000 * 1024),
        b_ih1, b_hh1, bx_gate, bh_gate, b_ih2, b_hh2, bias_g1, bias_g2,
        caps, emb, wembb);
  }
  // ---- merged transposes (1 launch)
  {
    TAll ta = {};
    int off = 0, j = 0;
    auto add = [&](const float* src, int ldsrc, int K, int N, __hip_bfloat16* dst,
                   int lddst, int koff, int noff) {
      int nbx = (N + 31) / 32, nby = (K + 31) / 32;
      ta.job[j] = {src, dst, ldsrc, K, N, lddst, koff, noff, off, nbx};
      off += nbx * nby;
      ++j;
    };
    add(W_img,   kH,     kRaw, kH,     WTimg,  kRaw, 0, 0);
    add(W_glob,  kE,     kH,   kE,     WTglob, kH,   0, 0);
    add(Wv,      kP,     kH,   kP,     WTv,    kH,   0, 0);
    // g1 dynamic: h2 rows of W_ih1 (K 0..1024) and W_hh1 (K 1024..2048)
    add(W_ih1,   4 * kH, 1024, 4 * kH, WTg1d,  2048, 0, 0);
    add(W_hh1,   4 * kH, 1024, 4 * kH, WTg1d,  2048, 1024, 0);
    add(Wx_gate, kH,     1024, kH,     WTg1d,  2048, 0, 4096);
    add(Wh_gate, kH,     1024, kH,     WTg1d,  2048, 1024, 4096);
    // g1 static: glob+we rows (src K-rows 1024..2048)
    add(W_ih1 + (size_t)1024 * 4 * kH, 4 * kH, 1024, 4 * kH, WTg1s, 1024, 0, 0);
    add(Wx_gate + (size_t)1024 * kH,   kH,     1024, kH,     WTg1s, 1024, 0, 4096);
    add(W_ih2,   4 * kH, 2048, 4 * kH, WTg2,   3072, 0, 0);
    add(W_hh2,   4 * kH, 1024, 4 * kH, WTg2,   3072, 2048, 0);
    add(W_fc,    kV,     kH,   kV,     WTfc,   kH,   0, 0);
    ta.njobs = j;
    ta.total_blocks = off;
    transpose_all<<<off, 256, 0, stream>>>(ta);
  }

  // Vfeat = relu(images @ W_img + b_img)   [4608 x 1024], K=2048  (128^2 tile)
  {
    G128Args ga = {};
    ga.A = imagesb; ga.lda = kRaw; ga.WT = WTimg; ga.ldk = kRaw; ga.bias = b_img;
    ga.C = Vfeat; ga.C16 = Vfeatb; ga.ldc = kH; ga.N = kH; ga.Ktot = kRaw;
    ga.act = 1; ga.cmap = 0; ga.morder = 0;
    gemm128<<<dim3(kH / 128, kB * kP / 128), 256, 0, stream>>>(ga);
  }
  mean_p<<<(kB * kH + 255) / 256, 256, 0, stream>>>(Vfeat, meanVb);
  // glob = relu(meanV @ W_glob + b_glob)
  {
    GemmBArgs ga = {};
    ga.seg[0] = {meanVb, kH, 0, kH};
    ga.nseg = 1; ga.WT = WTglob; ga.ldk = kH; ga.bias = b_glob;
    ga.C = nullptr; ga.C16 = globb; ga.ldc = kE; ga.N = kE; ga.Ktot = kH; ga.act = 1;
    gemm_bf16<<<dim3(kE / 64, kB / 64, 1), 256, 0, stream>>>(ga);
  }
  // Astat = [glob | we_t] rows, then static g1 GEMM over all (t,b)
  build_astat<<<(kT * kB * 1024 / 8 + 255) / 256, 256, 0, stream>>>(globb, wembb,
                                                                    (uint4*)Astat);
  {
    G128Args ga = {};
    ga.A = Astat; ga.lda = 1024; ga.WT = WTg1s; ga.ldk = 1024; ga.bias = bias_g1;
    ga.C = g1stat; ga.C16 = nullptr; ga.ldc = 5120; ga.N = 5120; ga.Ktot = 1024;
    ga.act = 0; ga.cmap = 0; ga.morder = 1;
    gemm128<<<dim3(5120 / 128, kT * kB / 128), 256, 0, stream>>>(ga);
  }
  // img_proj = Vfeat @ Wv + bv
  {
    GemmBArgs ga = {};
    ga.seg[0] = {Vfeatb, kH, 0, kH};
    ga.nseg = 1; ga.WT = WTv; ga.ldk = kH; ga.bias = bv;
    ga.C = img_proj; ga.C16 = nullptr; ga.ldc = kP; ga.N = kP; ga.Ktot = kH; ga.act = 0;
    gemm_bf16<<<dim3(1, kB * kP / 64, 1), 256, 0, stream>>>(ga);
  }

  // ---- 20 decode steps (4 kernels each; fc deferred, static hoisted)
  for (int t = 0; t < kT; ++t) {
    {  // g1 dynamic: [128 x 5120], K = 2048 (h2|h1), split-K=2
      GemmBArgs ga = {};
      ga.seg[0] = {h2b, kH, 0, kH};
      ga.seg[1] = {h1b, kH, kH, 2048};
      ga.nseg = 2; ga.WT = WTg1d; ga.ldk = 2048; ga.bias = nullptr;
      ga.C = g1out; ga.C16 = nullptr; ga.ldc = 5120; ga.N = 5120; ga.Ktot = 2048;
      ga.act = 0; ga.zstride = kSlab1;
      gemm_bf16<<<dim3(5120 / 64, kB / 64, 2), 256, 0, stream>>>(ga);
    }
    step1_fused<<<kB, 256, 0, stream>>>(g1out, g1stat, c1, h1b, img_proj, Vfeat,
                                        Wg, Ws_, bs_, wh, chat, chatb,
                                        out_alphas, out_betas, t);
    {  // g2: [128 x 4096], K = 3072, split-K=2
      GemmBArgs ga = {};
      ga.seg[0] = {chatb, kH, 0, kH};
      ga.seg[1] = {h1b, kH, kH, 2048};
      ga.seg[2] = {h2b, kH, 2048, 3072};
      ga.nseg = 3; ga.WT = WTg2; ga.ldk = 3072; ga.bias = nullptr;
      ga.C = g1out; ga.C16 = nullptr; ga.ldc = 4096; ga.N = 4096; ga.Ktot = 3072;
      ga.act = 0; ga.zstride = kSlab2;
      gemm_bf16<<<dim3(4096 / 64, kB / 64, 2), 256, 0, stream>>>(ga);
    }
    lstm2_elem<<<(kB * kH + 255) / 256, 256, 0, stream>>>(
        g1out, bias_g2, c2, h2b, chat, sbufall + (size_t)t * kB * kH);
  }

  // ---- batched fc over all steps: [2560 x 12000], K = 1024  (128^2 tile)
  {
    G128Args ga = {};
    ga.A = sbufall; ga.lda = kH; ga.WT = WTfc; ga.ldk = kH; ga.bias = b_fc;
    ga.C = out; ga.C16 = nullptr; ga.ldc = kT * kV; ga.N = kV; ga.Ktot = kH;
    ga.act = 0; ga.cmap = 1; ga.morder = 1;
    gemm128<<<dim3(12032 / 128, kT * kB / 128), 256, 0, stream>>>(ga);
  }
}

// Round 11
// 1537.440 us; speedup vs baseline: 1.4516x; 1.0311x over previous
//
#include <hip/hip_runtime.h>
#include <hip/hip_bf16.h>
#include <math.h>

typedef __attribute__((ext_vector_type(4))) float f32x4;
typedef __attribute__((ext_vector_type(8))) short bf16x8;

constexpr int kB = 128, kT = 20, kH = 1024, kE = 512, kP = 36, kRaw = 2048, kV = 12000;
constexpr int kSlab1 = kB * 5120;
constexpr int kSlab2 = kB * 4096;

__device__ __forceinline__ float sigf(float x) { return 1.0f / (1.0f + expf(-x)); }

#define AS1C const __attribute__((address_space(1))) void*
#define AS3P __attribute__((address_space(3))) void*

// ---------------------------------------------------------------- merged prep
constexpr int NZ1 = 2 * kB * kH / 4;        // float4 zeros over c1,c2
constexpr int NZ2 = 2 * kB * kH * 2 / 16;   // uint4 zeros over h1b,h2b
constexpr int NCV = kB * kP * kRaw / 4;     // images -> bf16 (4 per thread)
constexpr int NPV = 64 * 1024 * 2 / 16;     // WTv zero (uint4)
constexpr int NPF = 32 * 1024 * 2 / 16;     // WTfc pad zero (uint4)
constexpr int NPB = 5120;                   // pack biases
constexpr int NGE = kB * kT * kE;           // gather embeddings

__global__ __launch_bounds__(256) void prep_small(
    float* c1z, uint4* h1z, const float* images, __hip_bfloat16* imagesb,
    uint4* wtv, uint4* wtfc_pad,
    const float* b_ih1, const float* b_hh1, const float* bx, const float* bh,
    const float* b_ih2, const float* b_hh2, float* bias_g1, float* bias_g2,
    const int* caps, const float* emb, __hip_bfloat16* wembb) {
  long idx = (long)blockIdx.x * 256 + threadIdx.x;
  if (idx < NZ1) { reinterpret_cast<float4*>(c1z)[idx] = make_float4(0, 0, 0, 0); return; }
  idx -= NZ1;
  if (idx < NZ2) { h1z[idx] = make_uint4(0, 0, 0, 0); return; }
  idx -= NZ2;
  if (idx < NCV) {
    float4 v = reinterpret_cast<const float4*>(images)[idx];
    __hip_bfloat16* d = imagesb + idx * 4;
    d[0] = __float2bfloat16(v.x); d[1] = __float2bfloat16(v.y);
    d[2] = __float2bfloat16(v.z); d[3] = __float2bfloat16(v.w);
    return;
  }
  idx -= NCV;
  if (idx < NPV) { wtv[idx] = make_uint4(0, 0, 0, 0); return; }
  idx -= NPV;
  if (idx < NPF) { wtfc_pad[idx] = make_uint4(0, 0, 0, 0); return; }
  idx -= NPF;
  if (idx < NPB) {
    int i = (int)idx;
    if (i < 4096) {
      bias_g1[i] = b_ih1[i] + b_hh1[i];
      bias_g2[i] = b_ih2[i] + b_hh2[i];
    } else {
      bias_g1[i] = bx[i - 4096] + bh[i - 4096];
    }
    return;
  }
  idx -= NPB;
  if (idx < NGE) {
    int e = (int)(idx % kE);
    int bt = (int)(idx / kE);
    int t = bt % kT;
    int b = bt / kT;
    int tok = caps[b * (kT + 1) + t];
    wembb[idx] = __float2bfloat16(emb[(size_t)tok * kE + e]);
  }
}

// ------------------------------------------------ merged weight transposes
struct TJob {
  const float* src; __hip_bfloat16* dst;
  int ld_src, K, N, lddst, koff, noff, blk_off, nbx;
};
struct TAll { TJob job[12]; int njobs; int total_blocks; };

__global__ __launch_bounds__(256) void transpose_all(TAll ta) {
  __shared__ float t[32][33];
  int bid = blockIdx.x;
  int ji = 0;
  while (ji + 1 < ta.njobs && bid >= ta.job[ji + 1].blk_off) ++ji;
  const TJob& J = ta.job[ji];
  int lbid = bid - J.blk_off;
  int n0 = (lbid % J.nbx) * 32, k0 = (lbid / J.nbx) * 32;
  int tx = threadIdx.x & 31, ty = threadIdx.x >> 5;  // 32 x 8
  #pragma unroll
  for (int i = 0; i < 32; i += 8) {
    int k = k0 + ty + i, n = n0 + tx;
    t[ty + i][tx] = (k < J.K && n < J.N) ? J.src[(size_t)k * J.ld_src + n] : 0.0f;
  }
  __syncthreads();
  #pragma unroll
  for (int i = 0; i < 32; i += 8) {
    int n = n0 + ty + i, k = k0 + tx;
    if (n < J.N && k < J.K)
      J.dst[(size_t)(n + J.noff) * J.lddst + k + J.koff] = __float2bfloat16(t[tx][ty + i]);
  }
}

// ------------------------------------------------------- 64x64 bf16 MFMA GEMM
// BK=128, 2-buffer counted-vmcnt pipeline. Split-K via gridDim.z.
struct SegB { const __hip_bfloat16* A; int lda; int kstart; int kend; };
struct GemmBArgs {
  SegB seg[4]; int nseg;
  const __hip_bfloat16* WT; int ldk;
  const float* bias;
  float* C; __hip_bfloat16* C16; int ldc; int N; int Ktot; int act; int zstride;
};

__global__ __launch_bounds__(256) void gemm_bf16(GemmBArgs ga) {
  __shared__ char lds[65536];  // 2 bufs x (A 16K | B 16K)
  const int bm = blockIdx.y * 64;
  const int bn = blockIdx.x * 64;
  const int tid = threadIdx.x;
  const int lane = tid & 63;
  const int w = tid >> 6;
  const int wr = w >> 1, wc = w & 1;

  int rowS[4], scbS[4], dstS[4];
  #pragma unroll
  for (int j = 0; j < 4; ++j) {
    int off = ((j * 4 + w) * 64 + lane) * 16;   // linear byte in 16 KB tile
    int row = off >> 8, colb = off & 255;       // 256 B rows (BK=128)
    rowS[j] = row;
    scbS[j] = colb ^ ((row & 7) << 4);
    dstS[j] = (j * 4 + w) * 1024;
  }

  f32x4 acc[2][2] = {};
  const int nz = gridDim.z;
  const int nit = (ga.Ktot >> 7) / nz;
  const int it0 = blockIdx.z * nit;
  float* C = ga.C + (size_t)blockIdx.z * ga.zstride;

  auto stage = [&](int it, int buf) {
    const int k0 = it << 7;
    int si = 0;
    while (k0 >= ga.seg[si].kend) ++si;
    const __hip_bfloat16* Aseg = ga.seg[si].A;
    const int lda = ga.seg[si].lda;
    const int ks = k0 - ga.seg[si].kstart;
    char* baseA = lds + buf * 32768;
    char* baseB = baseA + 16384;
    #pragma unroll
    for (int j = 0; j < 4; ++j) {
      const __hip_bfloat16* sA = Aseg + (size_t)(bm + rowS[j]) * lda + ks + (scbS[j] >> 1);
      __builtin_amdgcn_global_load_lds((AS1C)sA, (AS3P)(baseA + dstS[j]), 16, 0, 0);
      const __hip_bfloat16* sB = ga.WT + (size_t)(bn + rowS[j]) * ga.ldk + k0 + (scbS[j] >> 1);
      __builtin_amdgcn_global_load_lds((AS1C)sB, (AS3P)(baseB + dstS[j]), 16, 0, 0);
    }
  };

  auto compute = [&](int buf) {
    const char* baseA = lds + buf * 32768;
    const char* baseB = baseA + 16384;
    #pragma unroll
    for (int kk = 0; kk < 4; ++kk) {
      bf16x8 a[2], b[2];
      #pragma unroll
      for (int f = 0; f < 2; ++f) {
        int row = wr * 32 + f * 16 + (lane & 15);
        int cb = kk * 64 + (lane >> 4) * 16;
        a[f] = *(const bf16x8*)(baseA + row * 256 + (cb ^ ((row & 7) << 4)));
        int nl = wc * 32 + f * 16 + (lane & 15);
        b[f] = *(const bf16x8*)(baseB + nl * 256 + (cb ^ ((nl & 7) << 4)));
      }
      #pragma unroll
      for (int fm = 0; fm < 2; ++fm)
        #pragma unroll
        for (int fn = 0; fn < 2; ++fn)
          acc[fm][fn] = __builtin_amdgcn_mfma_f32_16x16x32_bf16(a[fm], b[fn], acc[fm][fn], 0, 0, 0);
    }
  };

  stage(it0, 0);
  stage(it0 + 1, 1);
  asm volatile("s_waitcnt vmcnt(8)" ::: "memory");
  __builtin_amdgcn_s_barrier();
  int cur = 0;
  for (int i = 0; i < nit; ++i) {
    compute(cur);
    __builtin_amdgcn_s_barrier();
    if (i + 2 < nit) stage(it0 + i + 2, cur);
    if (i + 1 < nit) {
      if (i + 2 < nit) asm volatile("s_waitcnt vmcnt(8)" ::: "memory");
      else             asm volatile("s_waitcnt vmcnt(0)" ::: "memory");
      __builtin_amdgcn_s_barrier();
    }
    cur ^= 1;
  }

  #pragma unroll
  for (int fm = 0; fm < 2; ++fm) {
    int rbase = bm + wr * 32 + fm * 16 + (lane >> 4) * 4;
    #pragma unroll
    for (int fn = 0; fn < 2; ++fn) {
      int col = bn + wc * 32 + fn * 16 + (lane & 15);
      if (col >= ga.N) continue;
      float bv = ga.bias ? ga.bias[col] : 0.0f;
      #pragma unroll
      for (int j = 0; j < 4; ++j) {
        float v = acc[fm][fn][j] + bv;
        if (ga.act == 1) v = fmaxf(v, 0.0f);
        size_t off = (size_t)(rbase + j) * ga.ldc + col;
        if (ga.C) C[off] = v;
        if (ga.C16) ga.C16[off] = __float2bfloat16(v);
      }
    }
  }
}

// ------------------------------------------- 128x128 m97-structure bf16 GEMM
// Template BK: 64 (proven; 2 blocks/CU) or 32 (half LDS; 4 blocks/CU for
// latency-bound fc). 2-buffer counted vmcnt, bijective XCD swizzle.
// morder==1: bm-fastest in XCD chunk. cmap==1: row m -> C[(m&127)*ldc+(m>>7)*kV].
struct G128Args {
  const __hip_bfloat16* A; int lda;
  const __hip_bfloat16* WT; int ldk;
  const float* bias;
  float* C; __hip_bfloat16* C16; int ldc; int N; int Ktot; int act; int cmap; int morder;
};

template <int BK>
__global__ __launch_bounds__(256) void gemm128(G128Args ga) {
  constexpr int RB = BK * 2;               // row bytes
  constexpr int TILEB = 128 * RB;          // bytes per matrix tile
  constexpr int ROUNDS = TILEB / 4096;     // staging rounds (4 KB each)
  constexpr int SWZ = (RB == 256) ? 15 : (RB == 128 ? 7 : 3);
  __shared__ char lds[2 * 2 * TILEB];
  const int gx = gridDim.x;
  const int gy = gridDim.y;
  const int nwg = gx * gy;
  int bid = blockIdx.y * gx + blockIdx.x;
  int q = nwg >> 3, r = nwg & 7;
  int xc = bid & 7, yq = bid >> 3;
  int swz = (xc < r ? xc * (q + 1) : r * (q + 1) + (xc - r) * q) + yq;
  int bn, bm;
  if (ga.morder == 1) { bm = (swz % gy) * 128; bn = (swz / gy) * 128; }
  else                { bn = (swz % gx) * 128; bm = (swz / gx) * 128; }

  const int tid = threadIdx.x;
  const int lane = tid & 63;
  const int w = tid >> 6;
  const int wr = w >> 1, wc = w & 1;

  int rowS[ROUNDS], scbS[ROUNDS], dstS[ROUNDS];
  #pragma unroll
  for (int j = 0; j < ROUNDS; ++j) {
    int off = ((j * 4 + w) * 64 + lane) * 16;   // linear byte in tile
    int row = off / RB, colb = off % RB;
    rowS[j] = row;
    scbS[j] = colb ^ ((row & SWZ) << 4);
    dstS[j] = off;
  }

  f32x4 acc[4][4] = {};
  const int nit = ga.Ktot / BK;

  auto stage = [&](int it, int buf) {
    const int k0 = it * BK;
    char* baseA = lds + buf * 2 * TILEB;
    char* baseB = baseA + TILEB;
    #pragma unroll
    for (int j = 0; j < ROUNDS; ++j) {
      const __hip_bfloat16* sA = ga.A + (size_t)(bm + rowS[j]) * ga.lda + k0 + (scbS[j] >> 1);
      __builtin_amdgcn_global_load_lds((AS1C)sA, (AS3P)(baseA + dstS[j]), 16, 0, 0);
      const __hip_bfloat16* sB = ga.WT + (size_t)(bn + rowS[j]) * ga.ldk + k0 + (scbS[j] >> 1);
      __builtin_amdgcn_global_load_lds((AS1C)sB, (AS3P)(baseB + dstS[j]), 16, 0, 0);
    }
  };

  auto compute = [&](int buf) {
    const char* baseA = lds + buf * 2 * TILEB;
    const char* baseB = baseA + TILEB;
    #pragma unroll
    for (int kk = 0; kk < BK / 32; ++kk) {
      bf16x8 a[4], b[4];
      int cb = kk * 64 + (lane >> 4) * 16;
      #pragma unroll
      for (int f = 0; f < 4; ++f) {
        int row = wr * 64 + f * 16 + (lane & 15);
        a[f] = *(const bf16x8*)(baseA + row * RB + (cb ^ ((row & SWZ) << 4)));
        int nl = wc * 64 + f * 16 + (lane & 15);
        b[f] = *(const bf16x8*)(baseB + nl * RB + (cb ^ ((nl & SWZ) << 4)));
      }
      #pragma unroll
      for (int fm = 0; fm < 4; ++fm)
        #pragma unroll
        for (int fn = 0; fn < 4; ++fn)
          acc[fm][fn] = __builtin_amdgcn_mfma_f32_16x16x32_bf16(a[fm], b[fn], acc[fm][fn], 0, 0, 0);
    }
  };

  auto wait_one_stage = [&]() {
    if constexpr (ROUNDS == 4) asm volatile("s_waitcnt vmcnt(8)" ::: "memory");
    else                       asm volatile("s_waitcnt vmcnt(4)" ::: "memory");
  };

  stage(0, 0);
  stage(1, 1);
  wait_one_stage();
  __builtin_amdgcn_s_barrier();
  int cur = 0;
  for (int i = 0; i < nit; ++i) {
    compute(cur);
    __builtin_amdgcn_s_barrier();
    if (i + 2 < nit) stage(i + 2, cur);
    if (i + 1 < nit) {
      if (i + 2 < nit) wait_one_stage();
      else             asm volatile("s_waitcnt vmcnt(0)" ::: "memory");
      __builtin_amdgcn_s_barrier();
    }
    cur ^= 1;
  }

  #pragma unroll
  for (int fm = 0; fm < 4; ++fm) {
    int rbase = bm + wr * 64 + fm * 16 + (lane >> 4) * 4;
    #pragma unroll
    for (int fn = 0; fn < 4; ++fn) {
      int col = bn + wc * 64 + fn * 16 + (lane & 15);
      if (col >= ga.N) continue;
      float bv = ga.bias ? ga.bias[col] : 0.0f;
      #pragma unroll
      for (int j = 0; j < 4; ++j) {
        float v = acc[fm][fn][j] + bv;
        if (ga.act == 1) v = fmaxf(v, 0.0f);
        int m = rbase + j;
        size_t off = ga.cmap == 1
            ? (size_t)(m & 127) * ga.ldc + (size_t)(m >> 7) * kV + col
            : (size_t)m * ga.ldc + col;
        if (ga.C) ga.C[off] = v;
        if (ga.C16) ga.C16[off] = __float2bfloat16(v);
      }
    }
  }
}

// ------------------------------------------------------- small fused kernels
__global__ __launch_bounds__(256) void mean_p(const float* __restrict__ Vfeat,
                                              __hip_bfloat16* __restrict__ meanVb) {
  int idx = blockIdx.x * 256 + threadIdx.x;
  if (idx >= kB * kH) return;
  int b = idx >> 10, h = idx & 1023;
  float sm = 0.0f;
  for (int p = 0; p < kP; ++p) sm += Vfeat[((size_t)b * kP + p) * kH + h];
  meanVb[idx] = __float2bfloat16(sm * (1.0f / kP));
}

// LSTM1 gates + sentinel + full adaptive-attention step. One block per batch.
// g = THREE split-K slabs of [128][5120] raw sums; bias added here.
__global__ __launch_bounds__(256) void step1_fused(
    const float* __restrict__ g, const float* __restrict__ bias_g1,
    float* __restrict__ c1, __hip_bfloat16* __restrict__ h1b,
    const float* __restrict__ img_proj, const float* __restrict__ Vfeat,
    const float* __restrict__ Wg, const float* __restrict__ Ws,
    const float* __restrict__ bs, const float* __restrict__ wh,
    float* __restrict__ c_hat, __hip_bfloat16* __restrict__ c_hatb,
    float* __restrict__ out_alphas, float* __restrict__ out_betas, int t) {
  const int b = blockIdx.x;
  const int tid = threadIdx.x;
  const int lane = tid & 63;
  const int w = tid >> 6;
  __shared__ float sh_h1[kH];
  __shared__ float sh_st[kH];
  __shared__ float wsum[4][36];
  __shared__ float htp[36];
  __shared__ float stp[36];
  __shared__ float alpha[kP];
  __shared__ float sred[4];  // 0: att_vs, 1: beta, 2: zmax, 3: zsum

  const float* gr0 = g + (size_t)b * 5120;
  const float* gr1 = gr0 + kSlab1;
  const float* gr2 = gr1 + kSlab1;
  #pragma unroll
  for (int i = 0; i < 4; ++i) {
    int h = tid + i * 256;
    float ig = sigf(gr0[h]           + gr1[h]           + gr2[h]           + bias_g1[h]);
    float fg = sigf(gr0[kH + h]      + gr1[kH + h]      + gr2[kH + h]      + bias_g1[kH + h]);
    float gg = tanhf(gr0[2 * kH + h] + gr1[2 * kH + h]  + gr2[2 * kH + h]  + bias_g1[2 * kH + h]);
    float og = sigf(gr0[3 * kH + h]  + gr1[3 * kH + h]  + gr2[3 * kH + h]  + bias_g1[3 * kH + h]);
    int idx = b * kH + h;
    float c = fg * c1[idx] + ig * gg;
    float tc = tanhf(c);
    float hn = og * tc;
    c1[idx] = c;
    h1b[idx] = __float2bfloat16(hn);
    sh_h1[h] = hn;
    sh_st[h] = sigf(gr0[4 * kH + h] + gr1[4 * kH + h] + gr2[4 * kH + h] + bias_g1[4 * kH + h]) * tc;
  }
  __syncthreads();

  #pragma unroll
  for (int pass = 0; pass < 2; ++pass) {
    const float* vec = pass == 0 ? sh_h1 : sh_st;
    const float* W = pass == 0 ? Wg : Ws;
    float pg[36];
    #pragma unroll
    for (int j = 0; j < 36; ++j) pg[j] = 0.0f;
    #pragma unroll
    for (int i = 0; i < 4; ++i) {
      int hh = tid + i * 256;
      float hv = vec[hh];
      const float4* wrow = reinterpret_cast<const float4*>(W + (size_t)hh * 36);
      #pragma unroll
      for (int r = 0; r < 9; ++r) {
        float4 wv = wrow[r];
        pg[4 * r + 0] = fmaf(hv, wv.x, pg[4 * r + 0]);
        pg[4 * r + 1] = fmaf(hv, wv.y, pg[4 * r + 1]);
        pg[4 * r + 2] = fmaf(hv, wv.z, pg[4 * r + 2]);
        pg[4 * r + 3] = fmaf(hv, wv.w, pg[4 * r + 3]);
      }
    }
    #pragma unroll
    for (int j = 0; j < 36; ++j) {
      float v = pg[j];
      #pragma unroll
      for (int off = 32; off > 0; off >>= 1) v += __shfl_down(v, off, 64);
      if (lane == 0) wsum[w][j] = v;
    }
    __syncthreads();
    if (tid < 36) {
      float s = wsum[0][tid] + wsum[1][tid] + wsum[2][tid] + wsum[3][tid];
      if (pass == 0) htp[tid] = s; else stp[tid] = s;
    }
    __syncthreads();
  }

  if (w == 0) {
    float zz_r = -3.0e38f;
    if (lane < kP) {
      const float* ip = img_proj + ((size_t)b * kP + lane) * kP;
      float acc = 0.0f;
      #pragma unroll
      for (int j = 0; j < kP; ++j) acc = fmaf(tanhf(ip[j] + htp[j]), wh[j], acc);
      zz_r = acc;
    }
    float m = zz_r;
    #pragma unroll
    for (int off = 32; off > 0; off >>= 1) m = fmaxf(m, __shfl_xor(m, off, 64));
    float e = (lane < kP) ? expf(zz_r - m) : 0.0f;
    float s = e;
    #pragma unroll
    for (int off = 32; off > 0; off >>= 1) s += __shfl_xor(s, off, 64);
    if (lane < kP) alpha[lane] = e / s;
    if (lane == 0) { sred[2] = m; sred[3] = s; }
  } else if (w == 1) {
    float tv = 0.0f;
    if (lane < kP) tv = tanhf(stp[lane] + bs[lane] + htp[lane]) * wh[lane];
    #pragma unroll
    for (int off = 32; off > 0; off >>= 1) tv += __shfl_xor(tv, off, 64);
    if (lane == 0) sred[0] = tv;
  }
  __syncthreads();
  if (tid == 0) {
    float av = sred[0], m = sred[2], s = sred[3];
    float m2 = fmaxf(m, av);
    float eb = expf(av - m2);
    float beta = eb / (s * expf(m - m2) + eb);
    sred[1] = beta;
    out_betas[b * kT + t] = beta;
  }
  __syncthreads();
  if (tid < kP) out_alphas[((size_t)b * kT + t) * kP + tid] = alpha[tid];
  const float beta = sred[1];
  #pragma unroll
  for (int i = 0; i < 4; ++i) {
    int h = tid + i * 256;
    float ctx = 0.0f;
    for (int p = 0; p < kP; ++p) ctx = fmaf(alpha[p], Vfeat[((size_t)b * kP + p) * kH + h], ctx);
    float v = beta * sh_st[h] + (1.0f - beta) * ctx;
    c_hat[(size_t)b * kH + h] = v;
    c_hatb[(size_t)b * kH + h] = __float2bfloat16(v);
  }
}

// g: three split-K slabs of [128][4096] raw sums; bias added here.
__global__ __launch_bounds__(256) void lstm2_elem(const float* __restrict__ g,
                                                  const float* __restrict__ bias_g2,
                                                  float* __restrict__ c2,
                                                  __hip_bfloat16* __restrict__ h2b,
                                                  const float* __restrict__ c_hat,
                                                  __hip_bfloat16* __restrict__ sbufb) {
  int idx = blockIdx.x * 256 + threadIdx.x;
  if (idx >= kB * kH) return;
  int b = idx >> 10, h = idx & 1023;
  const float* gr0 = g + (size_t)b * 4 * kH;
  const float* gr1 = gr0 + kSlab2;
  const float* gr2 = gr1 + kSlab2;
  float ig = sigf(gr0[h]           + gr1[h]           + gr2[h]           + bias_g2[h]);
  float fg = sigf(gr0[kH + h]      + gr1[kH + h]      + gr2[kH + h]      + bias_g2[kH + h]);
  float gg = tanhf(gr0[2 * kH + h] + gr1[2 * kH + h]  + gr2[2 * kH + h]  + bias_g2[2 * kH + h]);
  float og = sigf(gr0[3 * kH + h]  + gr1[3 * kH + h]  + gr2[3 * kH + h]  + bias_g2[3 * kH + h]);
  float c = fg * c2[idx] + ig * gg;
  float hn = og * tanhf(c);
  c2[idx] = c;
  h2b[idx] = __float2bfloat16(hn);
  sbufb[idx] = __float2bfloat16(c_hat[idx] + hn);
}

// ------------------------------------------------------------------ launch
extern "C" void kernel_launch(void* const* d_in, const int* in_sizes, int n_in,
                              void* d_out, int out_size, void* d_ws, size_t ws_size,
                              hipStream_t stream) {
  const float* images  = (const float*)d_in[0];
  const int*   caps    = (const int*)d_in[1];
  const float* W_img   = (const float*)d_in[3];
  const float* b_img   = (const float*)d_in[4];
  const float* W_glob  = (const float*)d_in[5];
  const float* b_glob  = (const float*)d_in[6];
  const float* W_ih1   = (const float*)d_in[7];
  const float* W_hh1   = (const float*)d_in[8];
  const float* b_ih1   = (const float*)d_in[9];
  const float* b_hh1   = (const float*)d_in[10];
  const float* Wx_gate = (const float*)d_in[11];
  const float* bx_gate = (const float*)d_in[12];
  const float* Wh_gate = (const float*)d_in[13];
  const float* bh_gate = (const float*)d_in[14];
  const float* W_ih2   = (const float*)d_in[15];
  const float* W_hh2   = (const float*)d_in[16];
  const float* b_ih2   = (const float*)d_in[17];
  const float* b_hh2   = (const float*)d_in[18];
  const float* Wv      = (const float*)d_in[19];
  const float* bv      = (const float*)d_in[20];
  const float* Ws_     = (const float*)d_in[21];
  const float* bs_     = (const float*)d_in[22];
  const float* Wg      = (const float*)d_in[23];
  const float* wh      = (const float*)d_in[24];
  const float* emb     = (const float*)d_in[25];
  const float* W_fc    = (const float*)d_in[26];
  const float* b_fc    = (const float*)d_in[27];

  float* out = (float*)d_out;
  float* out_alphas = out + (size_t)kB * kT * kV;
  float* out_betas  = out_alphas + (size_t)kB * kT * kP;

  char* base = (char*)d_ws;
  auto alloc = [&](size_t bytes) {
    char* p = base;
    base += (bytes + 255) & ~(size_t)255;
    return p;
  };
  float*          Vfeat   = (float*)alloc((size_t)kB * kP * kH * 4);
  __hip_bfloat16* Vfeatb  = (__hip_bfloat16*)alloc((size_t)kB * kP * kH * 2);
  __hip_bfloat16* imagesb = (__hip_bfloat16*)alloc((size_t)kB * kP * kRaw * 2);
  __hip_bfloat16* WTg1    = (__hip_bfloat16*)alloc((size_t)5120 * 3072 * 2);
  __hip_bfloat16* WTg2    = (__hip_bfloat16*)alloc((size_t)4096 * 3072 * 2);
  __hip_bfloat16* WTfc    = (__hip_bfloat16*)alloc((size_t)12032 * 1024 * 2);
  __hip_bfloat16* WTimg   = (__hip_bfloat16*)alloc((size_t)1024 * 2048 * 2);
  __hip_bfloat16* WTglob  = (__hip_bfloat16*)alloc((size_t)512 * 1024 * 2);
  __hip_bfloat16* WTv     = (__hip_bfloat16*)alloc((size_t)64 * 1024 * 2);
  __hip_bfloat16* wembb   = (__hip_bfloat16*)alloc((size_t)kB * kT * kE * 2);
  float*          img_proj= (float*)alloc((size_t)kB * kP * kP * 4);
  __hip_bfloat16* globb   = (__hip_bfloat16*)alloc((size_t)kB * kE * 2);
  __hip_bfloat16* meanVb  = (__hip_bfloat16*)alloc((size_t)kB * kH * 2);
  float*          c1      = (float*)alloc((size_t)2 * kB * kH * 4);  // c1, c2
  float*          c2      = c1 + kB * kH;
  __hip_bfloat16* h1b     = (__hip_bfloat16*)alloc((size_t)2 * kB * kH * 2);
  __hip_bfloat16* h2b     = h1b + kB * kH;
  float*          g1out   = (float*)alloc((size_t)3 * kB * 5120 * 4);  // 3 slabs
  float*          chat    = (float*)alloc((size_t)kB * kH * 4);
  __hip_bfloat16* chatb   = (__hip_bfloat16*)alloc((size_t)kB * kH * 2);
  __hip_bfloat16* sbufall = (__hip_bfloat16*)alloc((size_t)kT * kB * kH * 2);  // [t][b][h]
  float*          bias_g1 = (float*)alloc(5120 * 4);
  float*          bias_g2 = (float*)alloc(4096 * 4);

  // ---- merged prep (1 launch)
  {
    long total = (long)NZ1 + NZ2 + NCV + NPV + NPF + NPB + NGE;
    int blocks = (int)((total + 255) / 256);
    prep_small<<<blocks, 256, 0, stream>>>(
        c1, (uint4*)h1b, images, imagesb, (uint4*)WTv,
        (uint4*)(WTfc + (size_t)12000 * 1024),
        b_ih1, b_hh1, bx_gate, bh_gate, b_ih2, b_hh2, bias_g1, bias_g2,
        caps, emb, wembb);
  }
  // ---- merged transposes (1 launch)
  {
    TAll ta = {};
    int off = 0, j = 0;
    auto add = [&](const float* src, int ldsrc, int K, int N, __hip_bfloat16* dst,
                   int lddst, int koff, int noff) {
      int nbx = (N + 31) / 32, nby = (K + 31) / 32;
      ta.job[j] = {src, dst, ldsrc, K, N, lddst, koff, noff, off, nbx};
      off += nbx * nby;
      ++j;
    };
    add(W_img,   kH,     kRaw, kH,     WTimg,  kRaw, 0, 0);
    add(W_glob,  kE,     kH,   kE,     WTglob, kH,   0, 0);
    add(Wv,      kP,     kH,   kP,     WTv,    kH,   0, 0);
    add(W_ih1,   4 * kH, 2048, 4 * kH, WTg1,   3072, 0, 0);
    add(W_hh1,   4 * kH, 1024, 4 * kH, WTg1,   3072, 2048, 0);
    add(Wx_gate, kH,     2048, kH,     WTg1,   3072, 0, 4096);
    add(Wh_gate, kH,     1024, kH,     WTg1,   3072, 2048, 4096);
    add(W_ih2,   4 * kH, 2048, 4 * kH, WTg2,   3072, 0, 0);
    add(W_hh2,   4 * kH, 1024, 4 * kH, WTg2,   3072, 2048, 0);
    add(W_fc,    kV,     kH,   kV,     WTfc,   kH,   0, 0);
    ta.njobs = j;
    ta.total_blocks = off;
    transpose_all<<<off, 256, 0, stream>>>(ta);
  }

  // Vfeat = relu(images @ W_img + b_img)   [4608 x 1024], K=2048  (BK=64)
  {
    G128Args ga = {};
    ga.A = imagesb; ga.lda = kRaw; ga.WT = WTimg; ga.ldk = kRaw; ga.bias = b_img;
    ga.C = Vfeat; ga.C16 = Vfeatb; ga.ldc = kH; ga.N = kH; ga.Ktot = kRaw;
    ga.act = 1; ga.cmap = 0; ga.morder = 0;
    gemm128<64><<<dim3(kH / 128, kB * kP / 128), 256, 0, stream>>>(ga);
  }
  mean_p<<<(kB * kH + 255) / 256, 256, 0, stream>>>(Vfeat, meanVb);
  // glob = relu(meanV @ W_glob + b_glob)
  {
    GemmBArgs ga = {};
    ga.seg[0] = {meanVb, kH, 0, kH};
    ga.nseg = 1; ga.WT = WTglob; ga.ldk = kH; ga.bias = b_glob;
    ga.C = nullptr; ga.C16 = globb; ga.ldc = kE; ga.N = kE; ga.Ktot = kH; ga.act = 1;
    gemm_bf16<<<dim3(kE / 64, kB / 64, 1), 256, 0, stream>>>(ga);
  }
  // img_proj = Vfeat @ Wv + bv
  {
    GemmBArgs ga = {};
    ga.seg[0] = {Vfeatb, kH, 0, kH};
    ga.nseg = 1; ga.WT = WTv; ga.ldk = kH; ga.bias = bv;
    ga.C = img_proj; ga.C16 = nullptr; ga.ldc = kP; ga.N = kP; ga.Ktot = kH; ga.act = 0;
    gemm_bf16<<<dim3(1, kB * kP / 64, 1), 256, 0, stream>>>(ga);
  }

  // ---- 20 decode steps (4 kernels each; fc deferred)
  for (int t = 0; t < kT; ++t) {
    {  // g1 + sentinel: [128 x 5120], K = 3072, split-K=3 (8 iters each)
      GemmBArgs ga = {};
      ga.seg[0] = {h2b, kH, 0, kH};
      ga.seg[1] = {globb, kE, kH, kH + kE};
      ga.seg[2] = {wembb + (size_t)t * kE, kT * kE, kH + kE, 2048};
      ga.seg[3] = {h1b, kH, 2048, 3072};
      ga.nseg = 4; ga.WT = WTg1; ga.ldk = 3072; ga.bias = nullptr;
      ga.C = g1out; ga.C16 = nullptr; ga.ldc = 5120; ga.N = 5120; ga.Ktot = 3072;
      ga.act = 0; ga.zstride = kSlab1;
      gemm_bf16<<<dim3(5120 / 64, kB / 64, 3), 256, 0, stream>>>(ga);
    }
    step1_fused<<<kB, 256, 0, stream>>>(g1out, bias_g1, c1, h1b, img_proj, Vfeat,
                                        Wg, Ws_, bs_, wh, chat, chatb,
                                        out_alphas, out_betas, t);
    {  // g2: [128 x 4096], K = 3072, split-K=3 (8 iters each)
      GemmBArgs ga = {};
      ga.seg[0] = {chatb, kH, 0, kH};
      ga.seg[1] = {h1b, kH, kH, 2048};
      ga.seg[2] = {h2b, kH, 2048, 3072};
      ga.nseg = 3; ga.WT = WTg2; ga.ldk = 3072; ga.bias = nullptr;
      ga.C = g1out; ga.C16 = nullptr; ga.ldc = 4096; ga.N = 4096; ga.Ktot = 3072;
      ga.act = 0; ga.zstride = kSlab2;
      gemm_bf16<<<dim3(4096 / 64, kB / 64, 3), 256, 0, stream>>>(ga);
    }
    lstm2_elem<<<(kB * kH + 255) / 256, 256, 0, stream>>>(
        g1out, bias_g2, c2, h2b, chat, sbufall + (size_t)t * kB * kH);
  }

  // ---- batched fc over all steps: [2560 x 12000], K = 1024  (BK=32, 4 blk/CU)
  {
    G128Args ga = {};
    ga.A = sbufall; ga.lda = kH; ga.WT = WTfc; ga.ldk = kH; ga.bias = b_fc;
    ga.C = out; ga.C16 = nullptr; ga.ldc = kT * kV; ga.N = kV; ga.Ktot = kH;
    ga.act = 0; ga.cmap = 1; ga.morder = 1;
    gemm128<32><<<dim3(12032 / 128, kT * kB / 128), 256, 0, stream>>>(ga);
  }
}